// Round 11
// baseline (641.782 us; speedup 1.0000x reference)
//
#include <hip/hip_runtime.h>

#define B_ 2
#define N_ 2048
#define DIM_ 640
#define NH_ 10
#define DH_ 64
#define DINNER_ 2560
#define L_ 4
#define FDIM_ 280
#define FDIMP_ 320
#define FEATD_ 576
#define NFEAT_ 19
#define ROWS_ (B_*N_)   /* 4096 */
#define NSPLIT_ 4
#define NT2_ 16         /* 32-key tiles per split (512 keys/split) */

typedef __attribute__((ext_vector_type(8))) unsigned short ushort8;
typedef __attribute__((ext_vector_type(4))) unsigned short ushort4v;
typedef __attribute__((ext_vector_type(4))) unsigned int u32x4;
typedef __attribute__((ext_vector_type(8))) __bf16 bf16x8;
typedef __attribute__((ext_vector_type(4))) __bf16 bf16x4;
typedef __attribute__((ext_vector_type(4))) float f32x4;
typedef __attribute__((ext_vector_type(2))) unsigned int u32x2;

static __device__ __forceinline__ unsigned short f2bf(float f){
  unsigned int u = __builtin_bit_cast(unsigned int, f);
  u += 0x7fffu + ((u >> 16) & 1u);
  return (unsigned short)(u >> 16);
}

static __device__ __forceinline__ void cvt4(const float* __restrict__ s, unsigned short* __restrict__ d){
  f32x4 v = *(const f32x4*)s;
  ushort4v r;
  r[0]=f2bf(v[0]); r[1]=f2bf(v[1]); r[2]=f2bf(v[2]); r[3]=f2bf(v[3]);
  *(ushort4v*)d = r;
}

static __device__ __forceinline__ f32x4 mfma16(ushort8 a, ushort8 b, f32x4 c){
  return __builtin_amdgcn_mfma_f32_16x16x32_bf16(
      __builtin_bit_cast(bf16x8, a), __builtin_bit_cast(bf16x8, b), c, 0, 0, 0);
}

#define GLD(src,dst) __builtin_amdgcn_global_load_lds((const __attribute__((address_space(1))) void*)(src), (__attribute__((address_space(3))) void*)(dst), 16, 0, 0)

// ---------------- fused prep (vectorized x4) ----------------
#define SEG0 4915200
#define SEG1 1638400
#define SEG2 6553600
#define SEG3 6553600
#define SEG4 179200
#define SEG5 89600
#define SEG6 89600
#define SEG7 655360
#define SEG8 655360
#define SEG9 4096
#define E0 SEG0
#define E9 (SEG0+SEG1+SEG2+SEG3+SEG4+SEG5+SEG6+SEG7+SEG8+SEG9)

__global__ __launch_bounds__(256) void prep_kernel(
    const float* __restrict__ qkv_w, const float* __restrict__ o_w,
    const float* __restrict__ p1_w, const float* __restrict__ p2_w,
    const float* __restrict__ lin1_w, const float* __restrict__ rb1_w,
    const float* __restrict__ rb2_w, const float* __restrict__ mask,
    unsigned short* __restrict__ qkvw, unsigned short* __restrict__ oww,
    unsigned short* __restrict__ p1w, unsigned short* __restrict__ p2w,
    unsigned short* __restrict__ l1w, unsigned short* __restrict__ r1w,
    unsigned short* __restrict__ r2w, unsigned int* __restrict__ hb1z,
    unsigned int* __restrict__ hb2z, float* __restrict__ mbb)
{
  for (int i = blockIdx.x*256 + threadIdx.x; i < E9/4; i += gridDim.x*256){
    int j = i*4;
    if (j < E0) { cvt4(qkv_w+j, qkvw+j); continue; }
    j -= E0;
    if (j < SEG1) { cvt4(o_w+j, oww+j); continue; }
    j -= SEG1;
    if (j < SEG2) { cvt4(p1_w+j, p1w+j); continue; }
    j -= SEG2;
    if (j < SEG3) { cvt4(p2_w+j, p2w+j); continue; }
    j -= SEG3;
    if (j < SEG4) { cvt4(lin1_w+j, l1w+j); continue; }
    j -= SEG4;
    if (j < SEG5) {
      #pragma unroll
      for (int e=0;e<4;e++){ int jj=j+e; int r=jj/FDIMP_, c=jj-r*FDIMP_;
        r1w[jj] = (c<FDIM_) ? f2bf(rb1_w[r*FDIM_+c]) : (unsigned short)0; }
      continue; }
    j -= SEG5;
    if (j < SEG6) {
      #pragma unroll
      for (int e=0;e<4;e++){ int jj=j+e; int r=jj/FDIMP_, c=jj-r*FDIMP_;
        r2w[jj] = (c<FDIM_) ? f2bf(rb2_w[r*FDIM_+c]) : (unsigned short)0; }
      continue; }
    j -= SEG6;
    if (j < SEG7) { *(u32x4*)(hb1z+j) = u32x4{0u,0u,0u,0u}; continue; }
    j -= SEG7;
    if (j < SEG8) { *(u32x4*)(hb2z+j) = u32x4{0u,0u,0u,0u}; continue; }
    j -= SEG8;
    {
      f32x4 m = *(const f32x4*)(mask+j);
      f32x4 r;
      #pragma unroll
      for (int e=0;e<4;e++) r[e] = (m[e] > 0.f) ? 0.f : -1e30f;
      *(f32x4*)(mbb+j) = r;
    }
  }
}

// ---------------- embedding ----------------
__global__ __launch_bounds__(256) void embed_kernel(const float* __restrict__ xf,
    const int* __restrict__ xt, const float* __restrict__ e0, const float* __restrict__ e1,
    const float* __restrict__ fw, const float* __restrict__ fb, float* __restrict__ Z){
  int row = blockIdx.x;
  __shared__ float f[NFEAT_];
  int t = threadIdx.x;
  if (t < NFEAT_) f[t] = xf[row*NFEAT_ + t];
  __syncthreads();
  if (t < 32) {
    int tok0 = xt[row*2];
    Z[(size_t)row*DIM_ + t] = e0[tok0*32 + t];
  } else if (t < 64) {
    int tok1 = xt[row*2+1];
    Z[(size_t)row*DIM_ + t] = e1[tok1*32 + (t-32)];
  }
  for (int fo = t; fo < FEATD_; fo += 256){
    float acc = fb[fo];
    #pragma unroll
    for (int k=0;k<NFEAT_;k++) acc += f[k]*fw[fo*NFEAT_+k];
    Z[(size_t)row*DIM_ + 64 + fo] = acc;
  }
}

// ---------------- layernorm (fp32 in -> bf16 out) ----------------
__global__ __launch_bounds__(256) void ln_kernel(const float* __restrict__ X,
    const float* __restrict__ g, const float* __restrict__ bb,
    unsigned short* __restrict__ out){
  int lane = threadIdx.x & 63;
  int row = blockIdx.x*4 + (threadIdx.x >> 6);
  const float* x = X + (size_t)row*DIM_;
  float v[10]; float s=0.f, sq=0.f;
  #pragma unroll
  for (int j=0;j<10;j++){ float t = x[lane + j*64]; v[j]=t; s+=t; sq+=t*t; }
  #pragma unroll
  for (int off=1; off<64; off<<=1){ s += __shfl_xor(s, off, 64); sq += __shfl_xor(sq, off, 64); }
  float mean = s*(1.f/DIM_);
  float var = sq*(1.f/DIM_) - mean*mean;
  float rstd = rsqrtf(var + 1e-5f);
  unsigned short* o = out + (size_t)row*DIM_;
  #pragma unroll
  for (int j=0;j<10;j++){ int c = lane + j*64; o[c] = f2bf((v[j]-mean)*rstd*g[c] + bb[c]); }
}

// ---------------- GEMM 128x128 tile, BK=64, swizzled LDS, 2-buf, XCD-chunked blocks ----------------
template<bool BIAS, bool RELU, bool RES, bool OUTF, bool OUTB>
__global__ __launch_bounds__(256) void gemm_kernel(
    const unsigned short* __restrict__ A, int lda,
    const unsigned short* __restrict__ Bw, int ldb,
    const float* __restrict__ bias,
    const float* __restrict__ Res, int ldres,
    float* __restrict__ Cf, int ldcf,
    unsigned short* __restrict__ Cb, int ldcb,
    int Ncols, int K)
{
  __shared__ __align__(128) unsigned short As[2][8192];
  __shared__ __align__(128) unsigned short Bs[2][8192];
  int t = threadIdx.x;
  int wid = t >> 6, lane = t & 63;
  int wr = wid >> 1, wc = wid & 1;
  int lg = lane >> 4, lm = lane & 15;
  int orig = blockIdx.y*gridDim.x + blockIdx.x;
  int nwg = gridDim.x*gridDim.y;
  int wg = ((orig & 7) * (nwg >> 3)) + (orig >> 3);
  int bx = wg % gridDim.x, by = wg / gridDim.x;
  int row0 = by * 128;
  int col0 = bx * 128;

  const unsigned short* aSrc[4];
  const unsigned short* bSrc[4];
  #pragma unroll
  for (int j=0;j<4;j++){
    int s = t + j*256;
    int r = s >> 3;
    int c = (s & 7) ^ (((r >> 2) & 1) << 1);
    aSrc[j] = A + (size_t)(row0 + r)*lda + c*8;
    int br = col0 + r; if (br >= Ncols) br = Ncols - 1;
    bSrc[j] = Bw + (size_t)br*ldb + c*8;
  }

  f32x4 acc[4][4];
  #pragma unroll
  for (int m=0;m<4;m++)
    #pragma unroll
    for (int n=0;n<4;n++) acc[m][n] = f32x4{0.f,0.f,0.f,0.f};

  int nk = K >> 6;
  #pragma unroll
  for (int j=0;j<4;j++){
    GLD(aSrc[j], &As[0][(t + j*256)*8]);
    GLD(bSrc[j], &Bs[0][(t + j*256)*8]);
  }

  int swz = (lm & 4) >> 1;
  for (int tk=0; tk<nk; ++tk){
    int cur = tk & 1;
    if (tk+1 < nk){
      int kt = (tk+1) << 6;
      #pragma unroll
      for (int j=0;j<4;j++){
        GLD(aSrc[j]+kt, &As[cur^1][(t + j*256)*8]);
        GLD(bSrc[j]+kt, &Bs[cur^1][(t + j*256)*8]);
      }
      asm volatile("s_waitcnt vmcnt(8)" ::: "memory");
    } else {
      asm volatile("s_waitcnt vmcnt(0)" ::: "memory");
    }
    __builtin_amdgcn_s_barrier();
    asm volatile("" ::: "memory");
    const unsigned short* Ac = &As[cur][0];
    const unsigned short* Bc = &Bs[cur][0];
    #pragma unroll
    for (int kk=0;kk<2;kk++){
      int ch = ((kk*4 + lg) ^ swz) * 8;
      ushort8 af[4], bfr[4];
      #pragma unroll
      for (int m=0;m<4;m++) af[m] = *(const ushort8*)(Ac + (wr*64 + m*16 + lm)*64 + ch);
      #pragma unroll
      for (int n=0;n<4;n++) bfr[n] = *(const ushort8*)(Bc + (wc*64 + n*16 + lm)*64 + ch);
      #pragma unroll
      for (int m=0;m<4;m++)
        #pragma unroll
        for (int n=0;n<4;n++)
          acc[m][n] = mfma16(af[m], bfr[n], acc[m][n]);
    }
    asm volatile("" ::: "memory");
    __builtin_amdgcn_s_barrier();
  }

  #pragma unroll
  for (int m=0;m<4;m++){
    int rbase = row0 + wr*64 + m*16 + lg*4;
    #pragma unroll
    for (int n=0;n<4;n++){
      int cc = col0 + wc*64 + n*16 + lm;
      if (cc < Ncols){
        float bv = 0.f;
        if (BIAS) bv = bias[cc];
        #pragma unroll
        for (int rr=0;rr<4;rr++){
          float v = acc[m][n][rr] + bv;
          if (RELU) v = fmaxf(v, 0.f);
          if (RES) v += Res[(size_t)(rbase+rr)*ldres + cc];
          if (OUTF) Cf[(size_t)(rbase+rr)*ldcf + cc] = v;
          if (OUTB) Cb[(size_t)(rbase+rr)*ldcb + cc] = f2bf(v);
        }
      }
    }
  }
}

// ---------------- GEMM 64x64 tile, BK=64, swizzled LDS, 2-buf, XCD-chunked ----------------
template<bool BIAS, bool RELU, bool RES, bool OUTF, bool OUTB>
__global__ __launch_bounds__(256) void gemm64_kernel(
    const unsigned short* __restrict__ A, int lda,
    const unsigned short* __restrict__ Bw, int ldb,
    const float* __restrict__ bias,
    const float* __restrict__ Res, int ldres,
    float* __restrict__ Cf, int ldcf,
    unsigned short* __restrict__ Cb, int ldcb,
    int Ncols, int K)
{
  __shared__ __align__(128) unsigned short As[2][64*64];
  __shared__ __align__(128) unsigned short Bs[2][64*64];
  int t = threadIdx.x;
  int wid = t >> 6, lane = t & 63;
  int wr = wid >> 1, wc = wid & 1;
  int lg = lane >> 4, lm = lane & 15;
  int orig = blockIdx.y*gridDim.x + blockIdx.x;
  int nwg = gridDim.x*gridDim.y;
  int wg = ((orig & 7) * (nwg >> 3)) + (orig >> 3);
  int bx = wg % gridDim.x, by = wg / gridDim.x;
  int row0 = by * 64;
  int col0 = bx * 64;

  int ar0 = t >> 3;
  int ar1 = ar0 + 32;
  int aq = (t & 7) ^ (((ar0 >> 2) & 1) << 1);
  const unsigned short* a0 = A + (size_t)(row0+ar0)*lda + aq*8;
  const unsigned short* a1 = A + (size_t)(row0+ar1)*lda + aq*8;
  int br0 = col0+ar0; if (br0 >= Ncols) br0 = Ncols-1;
  int br1 = col0+ar1; if (br1 >= Ncols) br1 = Ncols-1;
  const unsigned short* b0 = Bw + (size_t)br0*ldb + aq*8;
  const unsigned short* b1 = Bw + (size_t)br1*ldb + aq*8;
  int l0 = t*8, l1 = (t+256)*8;

  f32x4 acc[2][2];
  #pragma unroll
  for (int m=0;m<2;m++)
    #pragma unroll
    for (int n=0;n<2;n++) acc[m][n] = f32x4{0.f,0.f,0.f,0.f};

  int nk = K >> 6;
  GLD(a0, &As[0][l0]); GLD(b0, &Bs[0][l0]);
  GLD(a1, &As[0][l1]); GLD(b1, &Bs[0][l1]);

  int swz = (lm & 4) >> 1;
  for (int tk=0; tk<nk; ++tk){
    int cur = tk & 1;
    if (tk+1 < nk){
      int koff = (tk+1) << 6;
      GLD(a0+koff, &As[cur^1][l0]); GLD(b0+koff, &Bs[cur^1][l0]);
      GLD(a1+koff, &As[cur^1][l1]); GLD(b1+koff, &Bs[cur^1][l1]);
      asm volatile("s_waitcnt vmcnt(4)" ::: "memory");
    } else {
      asm volatile("s_waitcnt vmcnt(0)" ::: "memory");
    }
    __builtin_amdgcn_s_barrier();
    asm volatile("" ::: "memory");
    const unsigned short* Ac = &As[cur][0];
    const unsigned short* Bc = &Bs[cur][0];
    #pragma unroll
    for (int kk=0;kk<2;kk++){
      int ch = ((kk*4 + lg) ^ swz) * 8;
      ushort8 af[2], bfr[2];
      #pragma unroll
      for (int m=0;m<2;m++) af[m] = *(const ushort8*)(Ac + (wr*32 + m*16 + lm)*64 + ch);
      #pragma unroll
      for (int n=0;n<2;n++) bfr[n] = *(const ushort8*)(Bc + (wc*32 + n*16 + lm)*64 + ch);
      #pragma unroll
      for (int m=0;m<2;m++)
        #pragma unroll
        for (int n=0;n<2;n++)
          acc[m][n] = mfma16(af[m], bfr[n], acc[m][n]);
    }
    asm volatile("" ::: "memory");
    __builtin_amdgcn_s_barrier();
  }

  #pragma unroll
  for (int m=0;m<2;m++){
    int rbase = row0 + wr*32 + m*16 + lg*4;
    #pragma unroll
    for (int n=0;n<2;n++){
      int cc = col0 + wc*32 + n*16 + lm;
      if (cc < Ncols){
        float bv = 0.f;
        if (BIAS) bv = bias[cc];
        #pragma unroll
        for (int rr=0;rr<4;rr++){
          float v = acc[m][n][rr] + bv;
          if (RELU) v = fmaxf(v, 0.f);
          if (RES) v += Res[(size_t)(rbase+rr)*ldres + cc];
          if (OUTF) Cf[(size_t)(rbase+rr)*ldcf + cc] = v;
          if (OUTB) Cb[(size_t)(rbase+rr)*ldcb + cc] = f2bf(v);
        }
      }
    }
  }
}

// ---------------- flash attention, KV-split=4, KVBLK=32, 32 Q-rows/wave (QBLK=128)
// qkv bf16 [row][h*192 + {V:0,Q:64,K:128}+d]; mb = additive mask bias (0 / -1e30)
__global__ __launch_bounds__(256) void attn_kernel(const unsigned short* __restrict__ qkv,
    const float* __restrict__ mb, unsigned short* __restrict__ op, float* __restrict__ lpp){
  int bh = blockIdx.y; int b = bh/NH_, h = bh%NH_;
  int t = threadIdx.x; int wid = t>>6, lane = t&63, lg = lane>>4, lm = lane&15;
  int q0 = blockIdx.x*128 + wid*32;
  int k0 = blockIdx.z * (NT2_*32);
  size_t prow = (size_t)blockIdx.z*ROWS_ + b*N_;

  __shared__ __align__(128) unsigned short Ks[2][2048];
  __shared__ __align__(128) unsigned short Vs[2][2048];
  __shared__ __align__(16) float maskL[NT2_*32];

  const size_t base = (size_t)b*N_*1920 + (size_t)h*192;
  const size_t kvoff = (size_t)k0*1920;

  // staging (1 K-chunk + 1 V-chunk of 16B per thread per tile)
  int kk0 = t>>3, kc0 = (t&7)^(kk0&7);
  const unsigned short* kS0 = qkv + base + kvoff + 128 + (size_t)kk0*1920 + kc0*8;
  int vk0 = ((t>>5)<<2)|((t>>1)&3), vd0 = (((t>>3)&3)<<1)|(t&1);
  const unsigned short* vS0 = qkv + base + kvoff + (size_t)vk0*1920 + vd0*8;

  // two Q sub-tiles per wave: A = rows [q0, q0+16), B = [q0+16, q0+32)
  ushort8 qfA[2], qfB[2];
  #pragma unroll
  for (int ss=0; ss<2; ss++){
    qfA[ss] = *(const ushort8*)(qkv + base + (size_t)(q0+lm)*1920 + 64 + ss*32 + lg*8);
    qfB[ss] = *(const ushort8*)(qkv + base + (size_t)(q0+16+lm)*1920 + 64 + ss*32 + lg*8);
  }
  float cb2A = mb[b*N_ + q0 + lm] - 17.3123405f;
  float cb2B = mb[b*N_ + q0 + 16 + lm] - 17.3123405f;

  if (t < 128) GLD(mb + b*N_ + k0 + t*4, &maskL[t*4]);
  GLD(kS0, &Ks[0][t*8]);
  GLD(vS0, &Vs[0][t*8]);

  float lpA = 0.f, lpB = 0.f;
  f32x4 oA[4], oB[4];
  #pragma unroll
  for (int dn=0;dn<4;dn++){ oA[dn] = f32x4{0.f,0.f,0.f,0.f}; oB[dn] = f32x4{0.f,0.f,0.f,0.f}; }

  for (int ii=0; ii<NT2_; ++ii){
    int cur = ii & 1;
    if (ii < NT2_ - 1){
      const size_t adv = (size_t)(ii+1)*32*1920;
      GLD(kS0+adv, &Ks[1-cur][t*8]);
      GLD(vS0+adv, &Vs[1-cur][t*8]);
      asm volatile("s_waitcnt vmcnt(2)" ::: "memory");
    } else {
      asm volatile("s_waitcnt vmcnt(0)" ::: "memory");
    }
    __builtin_amdgcn_s_barrier();
    asm volatile("" ::: "memory");

    // ---- swapped QK^T for both sub-tiles (kf loaded once, used twice) ----
    const unsigned short* Kc = &Ks[cur][0];
    f32x4 sfA[2], sfB[2];
    #pragma unroll
    for (int c=0;c<2;c++){
      int krow = c*16 + lm;
      f32x4 sA = f32x4{0.f,0.f,0.f,0.f};
      f32x4 sB = f32x4{0.f,0.f,0.f,0.f};
      #pragma unroll
      for (int ss=0;ss<2;ss++){
        ushort8 kf = *(const ushort8*)(Kc + (krow*8 + ((ss*4+lg)^(krow&7)))*8);
        sA = mfma16(kf, qfA[ss], sA);
        sB = mfma16(kf, qfB[ss], sB);
      }
      sfA[c] = sA; sfB[c] = sB;
    }
    f32x4 mkv[2];
    #pragma unroll
    for (int c=0;c<2;c++) mkv[c] = *(const f32x4*)&maskL[ii*32 + c*16 + lg*4];

    // ---- 8 V transpose-reads (shared by both sub-tiles) ----
    unsigned vsb = (unsigned)(size_t)(__attribute__((address_space(3))) unsigned short*)&Vs[cur][0];
    unsigned a0 = vsb + lg*512 + lm*8;
    u32x2 vb[2][4];
    asm volatile(
      "ds_read_b64_tr_b16 %0, %4 offset:0\n\t"
      "ds_read_b64_tr_b16 %1, %4 offset:128\n\t"
      "ds_read_b64_tr_b16 %2, %4 offset:256\n\t"
      "ds_read_b64_tr_b16 %3, %4 offset:384"
      : "=&v"(vb[0][0]),"=&v"(vb[0][1]),"=&v"(vb[0][2]),"=&v"(vb[0][3]) : "v"(a0));
    asm volatile(
      "ds_read_b64_tr_b16 %0, %4 offset:2048\n\t"
      "ds_read_b64_tr_b16 %1, %4 offset:2176\n\t"
      "ds_read_b64_tr_b16 %2, %4 offset:2304\n\t"
      "ds_read_b64_tr_b16 %3, %4 offset:2432"
      : "=&v"(vb[1][0]),"=&v"(vb[1][1]),"=&v"(vb[1][2]),"=&v"(vb[1][3]) : "v"(a0));

    // ---- softmax numerators in-register (base-2, fixed shift) ----
    bf16x4 paA[2], paB[2];
    #pragma unroll
    for (int c=0;c<2;c++){
      float pm[4], pn[4];
      #pragma unroll
      for (int r=0;r<4;r++){
        pm[r] = __builtin_amdgcn_exp2f(fmaf(sfA[c][r], 0.18033688f, cb2A + mkv[c][r]));
        pn[r] = __builtin_amdgcn_exp2f(fmaf(sfB[c][r], 0.18033688f, cb2B + mkv[c][r]));
      }
      lpA += (pm[0]+pm[1]) + (pm[2]+pm[3]);
      lpB += (pn[0]+pn[1]) + (pn[2]+pn[3]);
      paA[c] = bf16x4{(__bf16)pm[0], (__bf16)pm[1], (__bf16)pm[2], (__bf16)pm[3]};
      paB[c] = bf16x4{(__bf16)pn[0], (__bf16)pn[1], (__bf16)pn[2], (__bf16)pn[3]};
    }

#define PVM(o_, p_, v_) asm("v_mfma_f32_16x16x16_bf16 %0, %1, %2, %0" \
      : "+v"(o_) : "v"(__builtin_bit_cast(u32x2, p_)), "v"(v_))
    asm volatile("s_waitcnt lgkmcnt(4)" ::: "memory");
    __builtin_amdgcn_sched_barrier(0);
    __builtin_amdgcn_s_setprio(1);
    PVM(oA[0],paA[0],vb[0][0]); PVM(oA[1],paA[0],vb[0][1]); PVM(oA[2],paA[0],vb[0][2]); PVM(oA[3],paA[0],vb[0][3]);
    PVM(oB[0],paB[0],vb[0][0]); PVM(oB[1],paB[0],vb[0][1]); PVM(oB[2],paB[0],vb[0][2]); PVM(oB[3],paB[0],vb[0][3]);
    asm volatile("s_waitcnt lgkmcnt(0)" ::: "memory");
    __builtin_amdgcn_sched_barrier(0);
    PVM(oA[0],paA[1],vb[1][0]); PVM(oA[1],paA[1],vb[1][1]); PVM(oA[2],paA[1],vb[1][2]); PVM(oA[3],paA[1],vb[1][3]);
    PVM(oB[0],paB[1],vb[1][0]); PVM(oB[1],paB[1],vb[1][1]); PVM(oB[2],paB[1],vb[1][2]); PVM(oB[3],paB[1],vb[1][3]);
    __builtin_amdgcn_s_setprio(0);
#undef PVM
    asm volatile("" ::: "memory");
    __builtin_amdgcn_s_barrier();
  }

  float sA = lpA, sB = lpB;
  sA += __shfl_xor(sA, 16, 64); sA += __shfl_xor(sA, 32, 64);
  sB += __shfl_xor(sB, 16, 64); sB += __shfl_xor(sB, 32, 64);
  if (lg == 0){
    lpp[(prow + q0 + lm)*NH_ + h] = sA;
    lpp[(prow + q0 + 16 + lm)*NH_ + h] = sB;
  }
  #pragma unroll
  for (int r=0;r<4;r++){
    unsigned short* obA = op + (prow + q0 + lg*4 + r)*DIM_ + h*64;
    unsigned short* obB = op + (prow + q0 + 16 + lg*4 + r)*DIM_ + h*64;
    #pragma unroll
    for (int dn=0;dn<4;dn++){
      obA[dn*16 + lm] = f2bf(oA[dn][r]);
      obB[dn*16 + lm] = f2bf(oB[dn][r]);
    }
  }
}

// ---------------- attention split-combine: sum 4 bf16 partials, normalize, leaky, bf16 ----------------
__global__ __launch_bounds__(256) void attnred_kernel(const unsigned short* __restrict__ op,
    const float* __restrict__ lpp, unsigned short* __restrict__ att){
  int idx = blockIdx.x*256 + threadIdx.x;      // [0, ROWS_*80)
  int row = idx / 80;
  int c8 = (idx - row*80) * 8;
  int h = c8 >> 6;
  float l = 0.f;
  #pragma unroll
  for (int s=0;s<NSPLIT_;s++) l += lpp[((size_t)s*ROWS_ + row)*NH_ + h];
  float inv = 1.0f / fmaxf(l, 1e-30f);
  float acc[8] = {0.f,0.f,0.f,0.f,0.f,0.f,0.f,0.f};
  #pragma unroll
  for (int s=0;s<NSPLIT_;s++){
    ushort8 v = *(const ushort8*)(op + ((size_t)s*ROWS_ + row)*DIM_ + c8);
    #pragma unroll
    for (int j=0;j<8;j++) acc[j] += __builtin_bit_cast(float, (unsigned)v[j] << 16);
  }
  ushort8 rr;
  #pragma unroll
  for (int j=0;j<8;j++){
    float v = acc[j] * inv;
    v = (v >= 0.f) ? v : 0.01f*v;   // leaky_relu fused
    rr[j] = f2bf(v);
  }
  *(ushort8*)(att + (size_t)row*DIM_ + c8) = rr;
}

// ---------------- final output dot ----------------
__global__ __launch_bounds__(256) void out_kernel(const float* __restrict__ hf,
    const float* __restrict__ ow, const float* __restrict__ ob, float* __restrict__ out){
  int lane = threadIdx.x & 63;
  int row = blockIdx.x*4 + (threadIdx.x>>6);
  const float* x = hf + (size_t)row*FDIM_;
  float s = 0.f;
  for (int j=lane;j<FDIM_;j+=64) s += x[j]*ow[j];
  #pragma unroll
  for (int off=1; off<64; off<<=1) s += __shfl_xor(s, off, 64);
  if (lane==0) out[row] = s + ob[0];
}

extern "C" void kernel_launch(void* const* d_in, const int* in_sizes, int n_in,
                              void* d_out, int out_size, void* d_ws, size_t ws_size,
                              hipStream_t stream)
{
  const float* x_feats = (const float*)d_in[0];
  const int*   x_toks  = (const int*)d_in[1];
  const float* mask    = (const float*)d_in[2];
  const float* emb0    = (const float*)d_in[3];
  const float* emb1    = (const float*)d_in[4];
  const float* feat_w  = (const float*)d_in[5];
  const float* feat_b  = (const float*)d_in[6];
  const float* qkv_w   = (const float*)d_in[7];
  const float* qkv_b   = (const float*)d_in[8];
  const float* o_w     = (const float*)d_in[9];
  const float* ln1_g   = (const float*)d_in[10];
  const float* ln1_b   = (const float*)d_in[11];
  const float* ln2_g   = (const float*)d_in[12];
  const float* ln2_b   = (const float*)d_in[13];
  const float* p1_w    = (const float*)d_in[14];
  const float* p1_b    = (const float*)d_in[15];
  const float* p2_w    = (const float*)d_in[16];
  const float* p2_b    = (const float*)d_in[17];
  const float* fn_g    = (const float*)d_in[18];
  const float* fn_b    = (const float*)d_in[19];
  const float* lin1_w  = (const float*)d_in[20];
  const float* lin1_b  = (const float*)d_in[21];
  const float* rb1_w   = (const float*)d_in[22];
  const float* rb1_b   = (const float*)d_in[23];
  const float* rb2_w   = (const float*)d_in[24];
  const float* rb2_b   = (const float*)d_in[25];
  const float* out_w   = (const float*)d_in[26];
  const float* out_b   = (const float*)d_in[27];
  float* out = (float*)d_out;

  char* w = (char*)d_ws;
  auto alloc = [&](size_t bytes)->void*{ void* p = (void*)w; w += (bytes + 255) & ~(size_t)255; return p; };

  float* Z              = (float*)alloc((size_t)ROWS_*DIM_*4);
  unsigned short* Zn    = (unsigned short*)alloc((size_t)ROWS_*DIM_*2);
  unsigned short* qkvB  = (unsigned short*)alloc((size_t)ROWS_*1920*2);
  unsigned short* attB  = (unsigned short*)alloc((size_t)ROWS_*DIM_*2);
  unsigned short* Hb    = (unsigned short*)alloc((size_t)ROWS_*DINNER_*2);
  float* hf             = (float*)alloc((size_t)ROWS_*FDIM_*4);
  unsigned short* hb1   = (unsigned short*)alloc((size_t)ROWS_*FDIMP_*2);
  unsigned short* hb2   = (unsigned short*)alloc((size_t)ROWS_*FDIMP_*2);
  float* mbb            = (float*)alloc((size_t)ROWS_*4);
  unsigned short* opart = (unsigned short*)alloc((size_t)NSPLIT_*ROWS_*DIM_*2);
  float* lpart          = (float*)alloc((size_t)NSPLIT_*ROWS_*NH_*4);
  unsigned short* qkvw  = (unsigned short*)alloc((size_t)L_*1920*DIM_*2);
  unsigned short* oww   = (unsigned short*)alloc((size_t)L_*DIM_*DIM_*2);
  unsigned short* p1w   = (unsigned short*)alloc((size_t)L_*DINNER_*DIM_*2);
  unsigned short* p2w   = (unsigned short*)alloc((size_t)L_*DIM_*DINNER_*2);
  unsigned short* l1w   = (unsigned short*)alloc((size_t)FDIM_*DIM_*2);
  unsigned short* r1w   = (unsigned short*)alloc((size_t)FDIM_*FDIMP_*2);
  unsigned short* r2w   = (unsigned short*)alloc((size_t)FDIM_*FDIMP_*2);

  prep_kernel<<<2048,256,0,stream>>>(qkv_w, o_w, p1_w, p2_w, lin1_w, rb1_w, rb2_w, mask,
      qkvw, oww, p1w, p2w, l1w, r1w, r2w,
      (unsigned int*)hb1, (unsigned int*)hb2, mbb);

  embed_kernel<<<ROWS_,256,0,stream>>>(x_feats, x_toks, emb0, emb1, feat_w, feat_b, Z);

  for (int l=0; l<L_; l++){
    ln_kernel<<<ROWS_/4,256,0,stream>>>(Z, ln1_g + l*DIM_, ln1_b + l*DIM_, Zn);
    gemm_kernel<true,false,false,false,true><<<dim3(15,32),256,0,stream>>>(
        Zn, DIM_, qkvw + (size_t)l*1920*DIM_, DIM_, qkv_b + l*1920,
        nullptr, 0, nullptr, 0, qkvB, 1920, 1920, DIM_);
    attn_kernel<<<dim3(N_/128, B_*NH_, NSPLIT_),256,0,stream>>>(qkvB, mbb, opart, lpart);
    attnred_kernel<<<ROWS_*80/256,256,0,stream>>>(opart, lpart, attB);
    gemm64_kernel<false,false,true,true,false><<<dim3(10,64),256,0,stream>>>(
        attB, DIM_, oww + (size_t)l*DIM_*DIM_, DIM_, nullptr,
        Z, DIM_, Z, DIM_, nullptr, 0, DIM_, DIM_);
    ln_kernel<<<ROWS_/4,256,0,stream>>>(Z, ln2_g + l*DIM_, ln2_b + l*DIM_, Zn);
    gemm_kernel<true,true,false,false,true><<<dim3(20,32),256,0,stream>>>(
        Zn, DIM_, p1w + (size_t)l*DINNER_*DIM_, DIM_, p1_b + l*DINNER_,
        nullptr, 0, nullptr, 0, Hb, DINNER_, DINNER_, DIM_);
    gemm64_kernel<true,false,true,true,false><<<dim3(10,64),256,0,stream>>>(
        Hb, DINNER_, p2w + (size_t)l*DIM_*DINNER_, DINNER_, p2_b + l*DIM_,
        Z, DIM_, Z, DIM_, nullptr, 0, DIM_, DINNER_);
  }

  ln_kernel<<<ROWS_/4,256,0,stream>>>(Z, fn_g, fn_b, Zn);
  gemm64_kernel<true,false,false,true,true><<<dim3(5,64),256,0,stream>>>(
      Zn, DIM_, l1w, DIM_, lin1_b, nullptr, 0, hf, FDIM_, hb1, FDIMP_, FDIM_, DIM_);
  gemm64_kernel<true,true,false,false,true><<<dim3(5,64),256,0,stream>>>(
      hb1, FDIMP_, r1w, FDIMP_, rb1_b, nullptr, 0, nullptr, 0, hb2, FDIMP_, FDIM_, FDIMP_);
  gemm64_kernel<true,false,true,true,false><<<dim3(5,64),256,0,stream>>>(
      hb2, FDIMP_, r2w, FDIMP_, rb2_b, hf, FDIM_, hf, FDIM_, nullptr, 0, FDIM_, FDIMP_);
  out_kernel<<<ROWS_/4,256,0,stream>>>(hf, out_w, out_b, out);
}

// Round 12
// 634.932 us; speedup vs baseline: 1.0108x; 1.0108x over previous
//
#include <hip/hip_runtime.h>

#define B_ 2
#define N_ 2048
#define DIM_ 640
#define NH_ 10
#define DH_ 64
#define DINNER_ 2560
#define L_ 4
#define FDIM_ 280
#define FDIMP_ 320
#define FEATD_ 576
#define NFEAT_ 19
#define ROWS_ (B_*N_)   /* 4096 */
#define NSPLIT_ 4
#define NT2_ 16         /* 32-key tiles per split (512 keys/split) */
#define NGRP_ (B_*NH_*NSPLIT_)   /* 80 (bh,split) groups */

typedef __attribute__((ext_vector_type(8))) unsigned short ushort8;
typedef __attribute__((ext_vector_type(4))) unsigned short ushort4v;
typedef __attribute__((ext_vector_type(4))) unsigned int u32x4;
typedef __attribute__((ext_vector_type(8))) __bf16 bf16x8;
typedef __attribute__((ext_vector_type(4))) __bf16 bf16x4;
typedef __attribute__((ext_vector_type(4))) float f32x4;
typedef __attribute__((ext_vector_type(2))) unsigned int u32x2;

static __device__ __forceinline__ unsigned short f2bf(float f){
  unsigned int u = __builtin_bit_cast(unsigned int, f);
  u += 0x7fffu + ((u >> 16) & 1u);
  return (unsigned short)(u >> 16);
}

static __device__ __forceinline__ void cvt4(const float* __restrict__ s, unsigned short* __restrict__ d){
  f32x4 v = *(const f32x4*)s;
  ushort4v r;
  r[0]=f2bf(v[0]); r[1]=f2bf(v[1]); r[2]=f2bf(v[2]); r[3]=f2bf(v[3]);
  *(ushort4v*)d = r;
}

static __device__ __forceinline__ f32x4 mfma16(ushort8 a, ushort8 b, f32x4 c){
  return __builtin_amdgcn_mfma_f32_16x16x32_bf16(
      __builtin_bit_cast(bf16x8, a), __builtin_bit_cast(bf16x8, b), c, 0, 0, 0);
}

#define GLD(src,dst) __builtin_amdgcn_global_load_lds((const __attribute__((address_space(1))) void*)(src), (__attribute__((address_space(3))) void*)(dst), 16, 0, 0)

// ---------------- fused prep (vectorized x4) ----------------
#define SEG0 4915200
#define SEG1 1638400
#define SEG2 6553600
#define SEG3 6553600
#define SEG4 179200
#define SEG5 89600
#define SEG6 89600
#define SEG7 655360
#define SEG8 655360
#define SEG9 4096
#define E0 SEG0
#define E9 (SEG0+SEG1+SEG2+SEG3+SEG4+SEG5+SEG6+SEG7+SEG8+SEG9)

__global__ __launch_bounds__(256) void prep_kernel(
    const float* __restrict__ qkv_w, const float* __restrict__ o_w,
    const float* __restrict__ p1_w, const float* __restrict__ p2_w,
    const float* __restrict__ lin1_w, const float* __restrict__ rb1_w,
    const float* __restrict__ rb2_w, const float* __restrict__ mask,
    unsigned short* __restrict__ qkvw, unsigned short* __restrict__ oww,
    unsigned short* __restrict__ p1w, unsigned short* __restrict__ p2w,
    unsigned short* __restrict__ l1w, unsigned short* __restrict__ r1w,
    unsigned short* __restrict__ r2w, unsigned int* __restrict__ hb1z,
    unsigned int* __restrict__ hb2z, float* __restrict__ mbb)
{
  for (int i = blockIdx.x*256 + threadIdx.x; i < E9/4; i += gridDim.x*256){
    int j = i*4;
    if (j < E0) { cvt4(qkv_w+j, qkvw+j); continue; }
    j -= E0;
    if (j < SEG1) { cvt4(o_w+j, oww+j); continue; }
    j -= SEG1;
    if (j < SEG2) { cvt4(p1_w+j, p1w+j); continue; }
    j -= SEG2;
    if (j < SEG3) { cvt4(p2_w+j, p2w+j); continue; }
    j -= SEG3;
    if (j < SEG4) { cvt4(lin1_w+j, l1w+j); continue; }
    j -= SEG4;
    if (j < SEG5) {
      #pragma unroll
      for (int e=0;e<4;e++){ int jj=j+e; int r=jj/FDIMP_, c=jj-r*FDIMP_;
        r1w[jj] = (c<FDIM_) ? f2bf(rb1_w[r*FDIM_+c]) : (unsigned short)0; }
      continue; }
    j -= SEG5;
    if (j < SEG6) {
      #pragma unroll
      for (int e=0;e<4;e++){ int jj=j+e; int r=jj/FDIMP_, c=jj-r*FDIMP_;
        r2w[jj] = (c<FDIM_) ? f2bf(rb2_w[r*FDIM_+c]) : (unsigned short)0; }
      continue; }
    j -= SEG6;
    if (j < SEG7) { *(u32x4*)(hb1z+j) = u32x4{0u,0u,0u,0u}; continue; }
    j -= SEG7;
    if (j < SEG8) { *(u32x4*)(hb2z+j) = u32x4{0u,0u,0u,0u}; continue; }
    j -= SEG8;
    {
      f32x4 m = *(const f32x4*)(mask+j);
      f32x4 r;
      #pragma unroll
      for (int e=0;e<4;e++) r[e] = (m[e] > 0.f) ? 0.f : -1e30f;
      *(f32x4*)(mbb+j) = r;
    }
  }
}

// ---------------- embedding ----------------
__global__ __launch_bounds__(256) void embed_kernel(const float* __restrict__ xf,
    const int* __restrict__ xt, const float* __restrict__ e0, const float* __restrict__ e1,
    const float* __restrict__ fw, const float* __restrict__ fb, float* __restrict__ Z){
  int row = blockIdx.x;
  __shared__ float f[NFEAT_];
  int t = threadIdx.x;
  if (t < NFEAT_) f[t] = xf[row*NFEAT_ + t];
  __syncthreads();
  if (t < 32) {
    int tok0 = xt[row*2];
    Z[(size_t)row*DIM_ + t] = e0[tok0*32 + t];
  } else if (t < 64) {
    int tok1 = xt[row*2+1];
    Z[(size_t)row*DIM_ + t] = e1[tok1*32 + (t-32)];
  }
  for (int fo = t; fo < FEATD_; fo += 256){
    float acc = fb[fo];
    #pragma unroll
    for (int k=0;k<NFEAT_;k++) acc += f[k]*fw[fo*NFEAT_+k];
    Z[(size_t)row*DIM_ + 64 + fo] = acc;
  }
}

// ---------------- layernorm (fp32 in -> bf16 out) ----------------
__global__ __launch_bounds__(256) void ln_kernel(const float* __restrict__ X,
    const float* __restrict__ g, const float* __restrict__ bb,
    unsigned short* __restrict__ out){
  int lane = threadIdx.x & 63;
  int row = blockIdx.x*4 + (threadIdx.x >> 6);
  const float* x = X + (size_t)row*DIM_;
  float v[10]; float s=0.f, sq=0.f;
  #pragma unroll
  for (int j=0;j<10;j++){ float t = x[lane + j*64]; v[j]=t; s+=t; sq+=t*t; }
  #pragma unroll
  for (int off=1; off<64; off<<=1){ s += __shfl_xor(s, off, 64); sq += __shfl_xor(sq, off, 64); }
  float mean = s*(1.f/DIM_);
  float var = sq*(1.f/DIM_) - mean*mean;
  float rstd = rsqrtf(var + 1e-5f);
  unsigned short* o = out + (size_t)row*DIM_;
  #pragma unroll
  for (int j=0;j<10;j++){ int c = lane + j*64; o[c] = f2bf((v[j]-mean)*rstd*g[c] + bb[c]); }
}

// ---------------- GEMM 128x128 tile, BK=64, swizzled LDS, 2-buf, XCD-chunked blocks ----------------
template<bool BIAS, bool RELU, bool RES, bool OUTF, bool OUTB>
__global__ __launch_bounds__(256) void gemm_kernel(
    const unsigned short* __restrict__ A, int lda,
    const unsigned short* __restrict__ Bw, int ldb,
    const float* __restrict__ bias,
    const float* __restrict__ Res, int ldres,
    float* __restrict__ Cf, int ldcf,
    unsigned short* __restrict__ Cb, int ldcb,
    int Ncols, int K)
{
  __shared__ __align__(128) unsigned short As[2][8192];
  __shared__ __align__(128) unsigned short Bs[2][8192];
  int t = threadIdx.x;
  int wid = t >> 6, lane = t & 63;
  int wr = wid >> 1, wc = wid & 1;
  int lg = lane >> 4, lm = lane & 15;
  int orig = blockIdx.y*gridDim.x + blockIdx.x;
  int nwg = gridDim.x*gridDim.y;
  int wg = ((orig & 7) * (nwg >> 3)) + (orig >> 3);
  int bx = wg % gridDim.x, by = wg / gridDim.x;
  int row0 = by * 128;
  int col0 = bx * 128;

  const unsigned short* aSrc[4];
  const unsigned short* bSrc[4];
  #pragma unroll
  for (int j=0;j<4;j++){
    int s = t + j*256;
    int r = s >> 3;
    int c = (s & 7) ^ (((r >> 2) & 1) << 1);
    aSrc[j] = A + (size_t)(row0 + r)*lda + c*8;
    int br = col0 + r; if (br >= Ncols) br = Ncols - 1;
    bSrc[j] = Bw + (size_t)br*ldb + c*8;
  }

  f32x4 acc[4][4];
  #pragma unroll
  for (int m=0;m<4;m++)
    #pragma unroll
    for (int n=0;n<4;n++) acc[m][n] = f32x4{0.f,0.f,0.f,0.f};

  int nk = K >> 6;
  #pragma unroll
  for (int j=0;j<4;j++){
    GLD(aSrc[j], &As[0][(t + j*256)*8]);
    GLD(bSrc[j], &Bs[0][(t + j*256)*8]);
  }

  int swz = (lm & 4) >> 1;
  for (int tk=0; tk<nk; ++tk){
    int cur = tk & 1;
    if (tk+1 < nk){
      int kt = (tk+1) << 6;
      #pragma unroll
      for (int j=0;j<4;j++){
        GLD(aSrc[j]+kt, &As[cur^1][(t + j*256)*8]);
        GLD(bSrc[j]+kt, &Bs[cur^1][(t + j*256)*8]);
      }
      asm volatile("s_waitcnt vmcnt(8)" ::: "memory");
    } else {
      asm volatile("s_waitcnt vmcnt(0)" ::: "memory");
    }
    __builtin_amdgcn_s_barrier();
    asm volatile("" ::: "memory");
    const unsigned short* Ac = &As[cur][0];
    const unsigned short* Bc = &Bs[cur][0];
    #pragma unroll
    for (int kk=0;kk<2;kk++){
      int ch = ((kk*4 + lg) ^ swz) * 8;
      ushort8 af[4], bfr[4];
      #pragma unroll
      for (int m=0;m<4;m++) af[m] = *(const ushort8*)(Ac + (wr*64 + m*16 + lm)*64 + ch);
      #pragma unroll
      for (int n=0;n<4;n++) bfr[n] = *(const ushort8*)(Bc + (wc*64 + n*16 + lm)*64 + ch);
      #pragma unroll
      for (int m=0;m<4;m++)
        #pragma unroll
        for (int n=0;n<4;n++)
          acc[m][n] = mfma16(af[m], bfr[n], acc[m][n]);
    }
    asm volatile("" ::: "memory");
    __builtin_amdgcn_s_barrier();
  }

  #pragma unroll
  for (int m=0;m<4;m++){
    int rbase = row0 + wr*64 + m*16 + lg*4;
    #pragma unroll
    for (int n=0;n<4;n++){
      int cc = col0 + wc*64 + n*16 + lm;
      if (cc < Ncols){
        float bv = 0.f;
        if (BIAS) bv = bias[cc];
        #pragma unroll
        for (int rr=0;rr<4;rr++){
          float v = acc[m][n][rr] + bv;
          if (RELU) v = fmaxf(v, 0.f);
          if (RES) v += Res[(size_t)(rbase+rr)*ldres + cc];
          if (OUTF) Cf[(size_t)(rbase+rr)*ldcf + cc] = v;
          if (OUTB) Cb[(size_t)(rbase+rr)*ldcb + cc] = f2bf(v);
        }
      }
    }
  }
}

// ---------------- GEMM 64x64 tile, BK=64, swizzled LDS, 2-buf, XCD-chunked ----------------
template<bool BIAS, bool RELU, bool RES, bool OUTF, bool OUTB>
__global__ __launch_bounds__(256) void gemm64_kernel(
    const unsigned short* __restrict__ A, int lda,
    const unsigned short* __restrict__ Bw, int ldb,
    const float* __restrict__ bias,
    const float* __restrict__ Res, int ldres,
    float* __restrict__ Cf, int ldcf,
    unsigned short* __restrict__ Cb, int ldcb,
    int Ncols, int K)
{
  __shared__ __align__(128) unsigned short As[2][64*64];
  __shared__ __align__(128) unsigned short Bs[2][64*64];
  int t = threadIdx.x;
  int wid = t >> 6, lane = t & 63;
  int wr = wid >> 1, wc = wid & 1;
  int lg = lane >> 4, lm = lane & 15;
  int orig = blockIdx.y*gridDim.x + blockIdx.x;
  int nwg = gridDim.x*gridDim.y;
  int wg = ((orig & 7) * (nwg >> 3)) + (orig >> 3);
  int bx = wg % gridDim.x, by = wg / gridDim.x;
  int row0 = by * 64;
  int col0 = bx * 64;

  int ar0 = t >> 3;
  int ar1 = ar0 + 32;
  int aq = (t & 7) ^ (((ar0 >> 2) & 1) << 1);
  const unsigned short* a0 = A + (size_t)(row0+ar0)*lda + aq*8;
  const unsigned short* a1 = A + (size_t)(row0+ar1)*lda + aq*8;
  int br0 = col0+ar0; if (br0 >= Ncols) br0 = Ncols-1;
  int br1 = col0+ar1; if (br1 >= Ncols) br1 = Ncols-1;
  const unsigned short* b0 = Bw + (size_t)br0*ldb + aq*8;
  const unsigned short* b1 = Bw + (size_t)br1*ldb + aq*8;
  int l0 = t*8, l1 = (t+256)*8;

  f32x4 acc[2][2];
  #pragma unroll
  for (int m=0;m<2;m++)
    #pragma unroll
    for (int n=0;n<2;n++) acc[m][n] = f32x4{0.f,0.f,0.f,0.f};

  int nk = K >> 6;
  GLD(a0, &As[0][l0]); GLD(b0, &Bs[0][l0]);
  GLD(a1, &As[0][l1]); GLD(b1, &Bs[0][l1]);

  int swz = (lm & 4) >> 1;
  for (int tk=0; tk<nk; ++tk){
    int cur = tk & 1;
    if (tk+1 < nk){
      int koff = (tk+1) << 6;
      GLD(a0+koff, &As[cur^1][l0]); GLD(b0+koff, &Bs[cur^1][l0]);
      GLD(a1+koff, &As[cur^1][l1]); GLD(b1+koff, &Bs[cur^1][l1]);
      asm volatile("s_waitcnt vmcnt(4)" ::: "memory");
    } else {
      asm volatile("s_waitcnt vmcnt(0)" ::: "memory");
    }
    __builtin_amdgcn_s_barrier();
    asm volatile("" ::: "memory");
    const unsigned short* Ac = &As[cur][0];
    const unsigned short* Bc = &Bs[cur][0];
    #pragma unroll
    for (int kk=0;kk<2;kk++){
      int ch = ((kk*4 + lg) ^ swz) * 8;
      ushort8 af[2], bfr[2];
      #pragma unroll
      for (int m=0;m<2;m++) af[m] = *(const ushort8*)(Ac + (wr*32 + m*16 + lm)*64 + ch);
      #pragma unroll
      for (int n=0;n<2;n++) bfr[n] = *(const ushort8*)(Bc + (wc*32 + n*16 + lm)*64 + ch);
      #pragma unroll
      for (int m=0;m<2;m++)
        #pragma unroll
        for (int n=0;n<2;n++)
          acc[m][n] = mfma16(af[m], bfr[n], acc[m][n]);
    }
    asm volatile("" ::: "memory");
    __builtin_amdgcn_s_barrier();
  }

  #pragma unroll
  for (int m=0;m<2;m++){
    int rbase = row0 + wr*32 + m*16 + lg*4;
    #pragma unroll
    for (int n=0;n<2;n++){
      int cc = col0 + wc*32 + n*16 + lm;
      if (cc < Ncols){
        float bv = 0.f;
        if (BIAS) bv = bias[cc];
        #pragma unroll
        for (int rr=0;rr<4;rr++){
          float v = acc[m][n][rr] + bv;
          if (RELU) v = fmaxf(v, 0.f);
          if (RES) v += Res[(size_t)(rbase+rr)*ldres + cc];
          if (OUTF) Cf[(size_t)(rbase+rr)*ldcf + cc] = v;
          if (OUTB) Cb[(size_t)(rbase+rr)*ldcb + cc] = f2bf(v);
        }
      }
    }
  }
}

// ---------------- flash attention, KV-split=4, KVBLK=32, XCD-grouped dispatch
// All 32 q-tile blocks of one (bh,split) group land on one XCD -> K/V stays in that L2.
// qkv bf16 [row][h*192 + {V:0,Q:64,K:128}+d]; mb = additive mask bias (0 / -1e30)
__global__ __launch_bounds__(256) void attn_kernel(const unsigned short* __restrict__ qkv,
    const float* __restrict__ mb, unsigned short* __restrict__ op, float* __restrict__ lpp){
  int t = threadIdx.x; int wid = t>>6, lane = t&63, lg = lane>>4, lm = lane&15;
  // XCD-grouping remap: XCD ~ linear%8; gz ≡ linear (mod 8) since NGRP_=80 ≡ 0 (mod 8)
  int Lid = blockIdx.x + gridDim.x*(blockIdx.y + gridDim.y*blockIdx.z);
  int qt = Lid / NGRP_;            // q-tile 0..31
  int gz = Lid - qt*NGRP_;         // (bh,split) group 0..79
  int bh = gz % (B_*NH_);
  int zz = gz / (B_*NH_);
  int b = bh/NH_, h = bh%NH_;
  int q0 = qt*64 + wid*16;
  int k0 = zz * (NT2_*32);
  size_t prow = (size_t)zz*ROWS_ + b*N_;

  __shared__ __align__(128) unsigned short Ks[2][2048];
  __shared__ __align__(128) unsigned short Vs[2][2048];
  __shared__ __align__(16) float maskL[NT2_*32];

  const size_t base = (size_t)b*N_*1920 + (size_t)h*192;
  const size_t kvoff = (size_t)k0*1920;

  // staging (1 K-chunk + 1 V-chunk of 16B per thread per tile)
  int kk0 = t>>3, kc0 = (t&7)^(kk0&7);
  const unsigned short* kS0 = qkv + base + kvoff + 128 + (size_t)kk0*1920 + kc0*8;
  int vk0 = ((t>>5)<<2)|((t>>1)&3), vd0 = (((t>>3)&3)<<1)|(t&1);
  const unsigned short* vS0 = qkv + base + kvoff + (size_t)vk0*1920 + vd0*8;

  ushort8 qf[2];
  #pragma unroll
  for (int ss=0; ss<2; ss++)
    qf[ss] = *(const ushort8*)(qkv + base + (size_t)(q0+lm)*1920 + 64 + ss*32 + lg*8);
  float cb2 = mb[b*N_ + q0 + lm] - 17.3123405f;

  if (t < 128) GLD(mb + b*N_ + k0 + t*4, &maskL[t*4]);
  GLD(kS0, &Ks[0][t*8]);
  GLD(vS0, &Vs[0][t*8]);

  float lp = 0.f;
  f32x4 o[4];
  #pragma unroll
  for (int dn=0;dn<4;dn++) o[dn] = f32x4{0.f,0.f,0.f,0.f};

  for (int ii=0; ii<NT2_; ++ii){
    int cur = ii & 1;
    if (ii < NT2_ - 1){
      const size_t adv = (size_t)(ii+1)*32*1920;
      GLD(kS0+adv, &Ks[1-cur][t*8]);
      GLD(vS0+adv, &Vs[1-cur][t*8]);
      asm volatile("s_waitcnt vmcnt(2)" ::: "memory");
    } else {
      asm volatile("s_waitcnt vmcnt(0)" ::: "memory");
    }
    __builtin_amdgcn_s_barrier();
    asm volatile("" ::: "memory");

    // ---- swapped QK^T: S^T[key][query=lm], 2 key-groups of 16 ----
    const unsigned short* Kc = &Ks[cur][0];
    f32x4 sf[2];
    #pragma unroll
    for (int c=0;c<2;c++){
      int krow = c*16 + lm;
      f32x4 s = f32x4{0.f,0.f,0.f,0.f};
      #pragma unroll
      for (int ss=0;ss<2;ss++){
        ushort8 kf = *(const ushort8*)(Kc + (krow*8 + ((ss*4+lg)^(krow&7)))*8);
        s = mfma16(kf, qf[ss], s);
      }
      sf[c] = s;
    }
    f32x4 mkv[2];
    #pragma unroll
    for (int c=0;c<2;c++) mkv[c] = *(const f32x4*)&maskL[ii*32 + c*16 + lg*4];

    // ---- 8 V transpose-reads (latency hides under softmax) ----
    unsigned vsb = (unsigned)(size_t)(__attribute__((address_space(3))) unsigned short*)&Vs[cur][0];
    unsigned a0 = vsb + lg*512 + lm*8;
    u32x2 vb[2][4];
    asm volatile(
      "ds_read_b64_tr_b16 %0, %4 offset:0\n\t"
      "ds_read_b64_tr_b16 %1, %4 offset:128\n\t"
      "ds_read_b64_tr_b16 %2, %4 offset:256\n\t"
      "ds_read_b64_tr_b16 %3, %4 offset:384"
      : "=&v"(vb[0][0]),"=&v"(vb[0][1]),"=&v"(vb[0][2]),"=&v"(vb[0][3]) : "v"(a0));
    asm volatile(
      "ds_read_b64_tr_b16 %0, %4 offset:2048\n\t"
      "ds_read_b64_tr_b16 %1, %4 offset:2176\n\t"
      "ds_read_b64_tr_b16 %2, %4 offset:2304\n\t"
      "ds_read_b64_tr_b16 %3, %4 offset:2432"
      : "=&v"(vb[1][0]),"=&v"(vb[1][1]),"=&v"(vb[1][2]),"=&v"(vb[1][3]) : "v"(a0));

    // ---- softmax numerators in-register (base-2, fixed shift) ----
    float pm[2][4]; bf16x4 pa[2];
    #pragma unroll
    for (int c=0;c<2;c++){
      #pragma unroll
      for (int r=0;r<4;r++){
        float x = fmaf(sf[c][r], 0.18033688f, cb2 + mkv[c][r]);
        pm[c][r] = __builtin_amdgcn_exp2f(x);
      }
      lp += (pm[c][0]+pm[c][1]) + (pm[c][2]+pm[c][3]);
      pa[c] = bf16x4{(__bf16)pm[c][0], (__bf16)pm[c][1], (__bf16)pm[c][2], (__bf16)pm[c][3]};
    }

#define PVM(dn_, c_) asm("v_mfma_f32_16x16x16_bf16 %0, %1, %2, %0" \
      : "+v"(o[dn_]) : "v"(__builtin_bit_cast(u32x2, pa[c_])), "v"(vb[c_][dn_]))
    asm volatile("s_waitcnt lgkmcnt(4)" ::: "memory");
    __builtin_amdgcn_sched_barrier(0);
    __builtin_amdgcn_s_setprio(1);
    PVM(0,0); PVM(1,0); PVM(2,0); PVM(3,0);
    asm volatile("s_waitcnt lgkmcnt(0)" ::: "memory");
    __builtin_amdgcn_sched_barrier(0);
    PVM(0,1); PVM(1,1); PVM(2,1); PVM(3,1);
    __builtin_amdgcn_s_setprio(0);
#undef PVM
    asm volatile("" ::: "memory");
    __builtin_amdgcn_s_barrier();
  }

  float s = lp;
  s += __shfl_xor(s, 16, 64);
  s += __shfl_xor(s, 32, 64);
  if (lg == 0) lpp[(prow + q0 + lm)*NH_ + h] = s;
  #pragma unroll
  for (int r=0;r<4;r++){
    unsigned short* ob = op + (prow + q0 + lg*4 + r)*DIM_ + h*64;
    #pragma unroll
    for (int dn=0;dn<4;dn++)
      ob[dn*16 + lm] = f2bf(o[dn][r]);
  }
}

// ---------------- attention split-combine: sum 4 bf16 partials, normalize, leaky, bf16 ----------------
__global__ __launch_bounds__(256) void attnred_kernel(const unsigned short* __restrict__ op,
    const float* __restrict__ lpp, unsigned short* __restrict__ att){
  int idx = blockIdx.x*256 + threadIdx.x;      // [0, ROWS_*80)
  int row = idx / 80;
  int c8 = (idx - row*80) * 8;
  int h = c8 >> 6;
  float l = 0.f;
  #pragma unroll
  for (int s=0;s<NSPLIT_;s++) l += lpp[((size_t)s*ROWS_ + row)*NH_ + h];
  float inv = 1.0f / fmaxf(l, 1e-30f);
  float acc[8] = {0.f,0.f,0.f,0.f,0.f,0.f,0.f,0.f};
  #pragma unroll
  for (int s=0;s<NSPLIT_;s++){
    ushort8 v = *(const ushort8*)(op + ((size_t)s*ROWS_ + row)*DIM_ + c8);
    #pragma unroll
    for (int j=0;j<8;j++) acc[j] += __builtin_bit_cast(float, (unsigned)v[j] << 16);
  }
  ushort8 rr;
  #pragma unroll
  for (int j=0;j<8;j++){
    float v = acc[j] * inv;
    v = (v >= 0.f) ? v : 0.01f*v;   // leaky_relu fused
    rr[j] = f2bf(v);
  }
  *(ushort8*)(att + (size_t)row*DIM_ + c8) = rr;
}

// ---------------- final output dot ----------------
__global__ __launch_bounds__(256) void out_kernel(const float* __restrict__ hf,
    const float* __restrict__ ow, const float* __restrict__ ob, float* __restrict__ out){
  int lane = threadIdx.x & 63;
  int row = blockIdx.x*4 + (threadIdx.x>>6);
  const float* x = hf + (size_t)row*FDIM_;
  float s = 0.f;
  for (int j=lane;j<FDIM_;j+=64) s += x[j]*ow[j];
  #pragma unroll
  for (int off=1; off<64; off<<=1) s += __shfl_xor(s, off, 64);
  if (lane==0) out[row] = s + ob[0];
}

extern "C" void kernel_launch(void* const* d_in, const int* in_sizes, int n_in,
                              void* d_out, int out_size, void* d_ws, size_t ws_size,
                              hipStream_t stream)
{
  const float* x_feats = (const float*)d_in[0];
  const int*   x_toks  = (const int*)d_in[1];
  const float* mask    = (const float*)d_in[2];
  const float* emb0    = (const float*)d_in[3];
  const float* emb1    = (const float*)d_in[4];
  const float* feat_w  = (const float*)d_in[5];
  const float* feat_b  = (const float*)d_in[6];
  const float* qkv_w   = (const float*)d_in[7];
  const float* qkv_b   = (const float*)d_in[8];
  const float* o_w     = (const float*)d_in[9];
  const float* ln1_g   = (const float*)d_in[10];
  const float* ln1_b   = (const float*)d_in[11];
  const float* ln2_g   = (const float*)d_in[12];
  const float* ln2_b   = (const float*)d_in[13];
  const float* p1_w    = (const float*)d_in[14];
  const float* p1_b    = (const float*)d_in[15];
  const float* p2_w    = (const float*)d_in[16];
  const float* p2_b    = (const float*)d_in[17];
  const float* fn_g    = (const float*)d_in[18];
  const float* fn_b    = (const float*)d_in[19];
  const float* lin1_w  = (const float*)d_in[20];
  const float* lin1_b  = (const float*)d_in[21];
  const float* rb1_w   = (const float*)d_in[22];
  const float* rb1_b   = (const float*)d_in[23];
  const float* rb2_w   = (const float*)d_in[24];
  const float* rb2_b   = (const float*)d_in[25];
  const float* out_w   = (const float*)d_in[26];
  const float* out_b   = (const float*)d_in[27];
  float* out = (float*)d_out;

  char* w = (char*)d_ws;
  auto alloc = [&](size_t bytes)->void*{ void* p = (void*)w; w += (bytes + 255) & ~(size_t)255; return p; };

  float* Z              = (float*)alloc((size_t)ROWS_*DIM_*4);
  unsigned short* Zn    = (unsigned short*)alloc((size_t)ROWS_*DIM_*2);
  unsigned short* qkvB  = (unsigned short*)alloc((size_t)ROWS_*1920*2);
  unsigned short* attB  = (unsigned short*)alloc((size_t)ROWS_*DIM_*2);
  unsigned short* Hb    = (unsigned short*)alloc((size_t)ROWS_*DINNER_*2);
  float* hf             = (float*)alloc((size_t)ROWS_*FDIM_*4);
  unsigned short* hb1   = (unsigned short*)alloc((size_t)ROWS_*FDIMP_*2);
  unsigned short* hb2   = (unsigned short*)alloc((size_t)ROWS_*FDIMP_*2);
  float* mbb            = (float*)alloc((size_t)ROWS_*4);
  unsigned short* opart = (unsigned short*)alloc((size_t)NSPLIT_*ROWS_*DIM_*2);
  float* lpart          = (float*)alloc((size_t)NSPLIT_*ROWS_*NH_*4);
  unsigned short* qkvw  = (unsigned short*)alloc((size_t)L_*1920*DIM_*2);
  unsigned short* oww   = (unsigned short*)alloc((size_t)L_*DIM_*DIM_*2);
  unsigned short* p1w   = (unsigned short*)alloc((size_t)L_*DINNER_*DIM_*2);
  unsigned short* p2w   = (unsigned short*)alloc((size_t)L_*DIM_*DINNER_*2);
  unsigned short* l1w   = (unsigned short*)alloc((size_t)FDIM_*DIM_*2);
  unsigned short* r1w   = (unsigned short*)alloc((size_t)FDIM_*FDIMP_*2);
  unsigned short* r2w   = (unsigned short*)alloc((size_t)FDIM_*FDIMP_*2);

  prep_kernel<<<2048,256,0,stream>>>(qkv_w, o_w, p1_w, p2_w, lin1_w, rb1_w, rb2_w, mask,
      qkvw, oww, p1w, p2w, l1w, r1w, r2w,
      (unsigned int*)hb1, (unsigned int*)hb2, mbb);

  embed_kernel<<<ROWS_,256,0,stream>>>(x_feats, x_toks, emb0, emb1, feat_w, feat_b, Z);

  for (int l=0; l<L_; l++){
    ln_kernel<<<ROWS_/4,256,0,stream>>>(Z, ln1_g + l*DIM_, ln1_b + l*DIM_, Zn);
    gemm_kernel<true,false,false,false,true><<<dim3(15,32),256,0,stream>>>(
        Zn, DIM_, qkvw + (size_t)l*1920*DIM_, DIM_, qkv_b + l*1920,
        nullptr, 0, nullptr, 0, qkvB, 1920, 1920, DIM_);
    attn_kernel<<<dim3(N_/64, B_*NH_, NSPLIT_),256,0,stream>>>(qkvB, mbb, opart, lpart);
    attnred_kernel<<<ROWS_*80/256,256,0,stream>>>(opart, lpart, attB);
    gemm64_kernel<false,false,true,true,false><<<dim3(10,64),256,0,stream>>>(
        attB, DIM_, oww + (size_t)l*DIM_*DIM_, DIM_, nullptr,
        Z, DIM_, Z, DIM_, nullptr, 0, DIM_, DIM_);
    ln_kernel<<<ROWS_/4,256,0,stream>>>(Z, ln2_g + l*DIM_, ln2_b + l*DIM_, Zn);
    gemm_kernel<true,true,false,false,true><<<dim3(20,32),256,0,stream>>>(
        Zn, DIM_, p1w + (size_t)l*DINNER_*DIM_, DIM_, p1_b + l*DINNER_,
        nullptr, 0, nullptr, 0, Hb, DINNER_, DINNER_, DIM_);
    gemm64_kernel<true,false,true,true,false><<<dim3(10,64),256,0,stream>>>(
        Hb, DINNER_, p2w + (size_t)l*DIM_*DINNER_, DINNER_, p2_b + l*DIM_,
        Z, DIM_, Z, DIM_, nullptr, 0, DIM_, DINNER_);
  }

  ln_kernel<<<ROWS_/4,256,0,stream>>>(Z, fn_g, fn_b, Zn);
  gemm64_kernel<true,false,false,true,true><<<dim3(5,64),256,0,stream>>>(
      Zn, DIM_, l1w, DIM_, lin1_b, nullptr, 0, hf, FDIM_, hb1, FDIMP_, FDIM_, DIM_);
  gemm64_kernel<true,true,false,false,true><<<dim3(5,64),256,0,stream>>>(
      hb1, FDIMP_, r1w, FDIMP_, rb1_b, nullptr, 0, nullptr, 0, hb2, FDIMP_, FDIM_, FDIMP_);
  gemm64_kernel<true,false,true,true,false><<<dim3(5,64),256,0,stream>>>(
      hb2, FDIMP_, r2w, FDIMP_, rb2_b, hf, FDIM_, hf, FDIM_, nullptr, 0, FDIM_, FDIMP_);
  out_kernel<<<ROWS_/4,256,0,stream>>>(hf, out_w, out_b, out);
}

// Round 13
// 628.040 us; speedup vs baseline: 1.0219x; 1.0110x over previous
//
#include <hip/hip_runtime.h>

#define B_ 2
#define N_ 2048
#define DIM_ 640
#define NH_ 10
#define DH_ 64
#define DINNER_ 2560
#define L_ 4
#define FDIM_ 280
#define FDIMP_ 320
#define FEATD_ 576
#define NFEAT_ 19
#define ROWS_ (B_*N_)   /* 4096 */
#define NSPLIT_ 4
#define NT2_ 16         /* 32-key tiles per split (512 keys/split) */
#define NGRP_ (B_*NH_*NSPLIT_)   /* 80 (bh,split) groups */

typedef __attribute__((ext_vector_type(8))) unsigned short ushort8;
typedef __attribute__((ext_vector_type(4))) unsigned short ushort4v;
typedef __attribute__((ext_vector_type(4))) unsigned int u32x4;
typedef __attribute__((ext_vector_type(8))) __bf16 bf16x8;
typedef __attribute__((ext_vector_type(4))) __bf16 bf16x4;
typedef __attribute__((ext_vector_type(4))) float f32x4;
typedef __attribute__((ext_vector_type(2))) unsigned int u32x2;

static __device__ __forceinline__ unsigned short f2bf(float f){
  unsigned int u = __builtin_bit_cast(unsigned int, f);
  u += 0x7fffu + ((u >> 16) & 1u);
  return (unsigned short)(u >> 16);
}

static __device__ __forceinline__ void cvt4(const float* __restrict__ s, unsigned short* __restrict__ d){
  f32x4 v = *(const f32x4*)s;
  ushort4v r;
  r[0]=f2bf(v[0]); r[1]=f2bf(v[1]); r[2]=f2bf(v[2]); r[3]=f2bf(v[3]);
  *(ushort4v*)d = r;
}

static __device__ __forceinline__ f32x4 mfma16(ushort8 a, ushort8 b, f32x4 c){
  return __builtin_amdgcn_mfma_f32_16x16x32_bf16(
      __builtin_bit_cast(bf16x8, a), __builtin_bit_cast(bf16x8, b), c, 0, 0, 0);
}

#define GLD(src,dst) __builtin_amdgcn_global_load_lds((const __attribute__((address_space(1))) void*)(src), (__attribute__((address_space(3))) void*)(dst), 16, 0, 0)

// ---------------- fused prep (vectorized x4) ----------------
#define SEG0 4915200
#define SEG1 1638400
#define SEG2 6553600
#define SEG3 6553600
#define SEG4 179200
#define SEG5 89600
#define SEG6 89600
#define SEG7 655360
#define SEG8 655360
#define SEG9 4096
#define E0 SEG0
#define E9 (SEG0+SEG1+SEG2+SEG3+SEG4+SEG5+SEG6+SEG7+SEG8+SEG9)

__global__ __launch_bounds__(256) void prep_kernel(
    const float* __restrict__ qkv_w, const float* __restrict__ o_w,
    const float* __restrict__ p1_w, const float* __restrict__ p2_w,
    const float* __restrict__ lin1_w, const float* __restrict__ rb1_w,
    const float* __restrict__ rb2_w, const float* __restrict__ mask,
    unsigned short* __restrict__ qkvw, unsigned short* __restrict__ oww,
    unsigned short* __restrict__ p1w, unsigned short* __restrict__ p2w,
    unsigned short* __restrict__ l1w, unsigned short* __restrict__ r1w,
    unsigned short* __restrict__ r2w, unsigned int* __restrict__ hb1z,
    unsigned int* __restrict__ hb2z, float* __restrict__ mbb)
{
  for (int i = blockIdx.x*256 + threadIdx.x; i < E9/4; i += gridDim.x*256){
    int j = i*4;
    if (j < E0) { cvt4(qkv_w+j, qkvw+j); continue; }
    j -= E0;
    if (j < SEG1) { cvt4(o_w+j, oww+j); continue; }
    j -= SEG1;
    if (j < SEG2) { cvt4(p1_w+j, p1w+j); continue; }
    j -= SEG2;
    if (j < SEG3) { cvt4(p2_w+j, p2w+j); continue; }
    j -= SEG3;
    if (j < SEG4) { cvt4(lin1_w+j, l1w+j); continue; }
    j -= SEG4;
    if (j < SEG5) {
      #pragma unroll
      for (int e=0;e<4;e++){ int jj=j+e; int r=jj/FDIMP_, c=jj-r*FDIMP_;
        r1w[jj] = (c<FDIM_) ? f2bf(rb1_w[r*FDIM_+c]) : (unsigned short)0; }
      continue; }
    j -= SEG5;
    if (j < SEG6) {
      #pragma unroll
      for (int e=0;e<4;e++){ int jj=j+e; int r=jj/FDIMP_, c=jj-r*FDIMP_;
        r2w[jj] = (c<FDIM_) ? f2bf(rb2_w[r*FDIM_+c]) : (unsigned short)0; }
      continue; }
    j -= SEG6;
    if (j < SEG7) { *(u32x4*)(hb1z+j) = u32x4{0u,0u,0u,0u}; continue; }
    j -= SEG7;
    if (j < SEG8) { *(u32x4*)(hb2z+j) = u32x4{0u,0u,0u,0u}; continue; }
    j -= SEG8;
    {
      f32x4 m = *(const f32x4*)(mask+j);
      f32x4 r;
      #pragma unroll
      for (int e=0;e<4;e++) r[e] = (m[e] > 0.f) ? 0.f : -1e30f;
      *(f32x4*)(mbb+j) = r;
    }
  }
}

// ---------------- embedding ----------------
__global__ __launch_bounds__(256) void embed_kernel(const float* __restrict__ xf,
    const int* __restrict__ xt, const float* __restrict__ e0, const float* __restrict__ e1,
    const float* __restrict__ fw, const float* __restrict__ fb, float* __restrict__ Z){
  int row = blockIdx.x;
  __shared__ float f[NFEAT_];
  int t = threadIdx.x;
  if (t < NFEAT_) f[t] = xf[row*NFEAT_ + t];
  __syncthreads();
  if (t < 32) {
    int tok0 = xt[row*2];
    Z[(size_t)row*DIM_ + t] = e0[tok0*32 + t];
  } else if (t < 64) {
    int tok1 = xt[row*2+1];
    Z[(size_t)row*DIM_ + t] = e1[tok1*32 + (t-32)];
  }
  for (int fo = t; fo < FEATD_; fo += 256){
    float acc = fb[fo];
    #pragma unroll
    for (int k=0;k<NFEAT_;k++) acc += f[k]*fw[fo*NFEAT_+k];
    Z[(size_t)row*DIM_ + 64 + fo] = acc;
  }
}

// ---------------- layernorm (fp32 in -> bf16 out) ----------------
__global__ __launch_bounds__(256) void ln_kernel(const float* __restrict__ X,
    const float* __restrict__ g, const float* __restrict__ bb,
    unsigned short* __restrict__ out){
  int lane = threadIdx.x & 63;
  int row = blockIdx.x*4 + (threadIdx.x >> 6);
  const float* x = X + (size_t)row*DIM_;
  float v[10]; float s=0.f, sq=0.f;
  #pragma unroll
  for (int j=0;j<10;j++){ float t = x[lane + j*64]; v[j]=t; s+=t; sq+=t*t; }
  #pragma unroll
  for (int off=1; off<64; off<<=1){ s += __shfl_xor(s, off, 64); sq += __shfl_xor(sq, off, 64); }
  float mean = s*(1.f/DIM_);
  float var = sq*(1.f/DIM_) - mean*mean;
  float rstd = rsqrtf(var + 1e-5f);
  unsigned short* o = out + (size_t)row*DIM_;
  #pragma unroll
  for (int j=0;j<10;j++){ int c = lane + j*64; o[c] = f2bf((v[j]-mean)*rstd*g[c] + bb[c]); }
}

// ---------------- GEMM 128x128 tile, BK=64, FULL (r&7) LDS swizzle, 2-buf, XCD-chunked ----------------
// chunk c stored at c' = c ^ (r&7); read chunk ((kk*4+lg) ^ (lm&7)) -> 8 lanes per 4-bank window = conflict-free
template<bool BIAS, bool RELU, bool RES, bool OUTF, bool OUTB>
__global__ __launch_bounds__(256) void gemm_kernel(
    const unsigned short* __restrict__ A, int lda,
    const unsigned short* __restrict__ Bw, int ldb,
    const float* __restrict__ bias,
    const float* __restrict__ Res, int ldres,
    float* __restrict__ Cf, int ldcf,
    unsigned short* __restrict__ Cb, int ldcb,
    int Ncols, int K)
{
  __shared__ __align__(128) unsigned short As[2][8192];
  __shared__ __align__(128) unsigned short Bs[2][8192];
  int t = threadIdx.x;
  int wid = t >> 6, lane = t & 63;
  int wr = wid >> 1, wc = wid & 1;
  int lg = lane >> 4, lm = lane & 15;
  int orig = blockIdx.y*gridDim.x + blockIdx.x;
  int nwg = gridDim.x*gridDim.y;
  int wg = ((orig & 7) * (nwg >> 3)) + (orig >> 3);
  int bx = wg % gridDim.x, by = wg / gridDim.x;
  int row0 = by * 128;
  int col0 = bx * 128;

  const unsigned short* aSrc[4];
  const unsigned short* bSrc[4];
  #pragma unroll
  for (int j=0;j<4;j++){
    int s = t + j*256;
    int r = s >> 3;
    int c = (s & 7) ^ (r & 7);
    aSrc[j] = A + (size_t)(row0 + r)*lda + c*8;
    int br = col0 + r; if (br >= Ncols) br = Ncols - 1;
    bSrc[j] = Bw + (size_t)br*ldb + c*8;
  }

  f32x4 acc[4][4];
  #pragma unroll
  for (int m=0;m<4;m++)
    #pragma unroll
    for (int n=0;n<4;n++) acc[m][n] = f32x4{0.f,0.f,0.f,0.f};

  int nk = K >> 6;
  #pragma unroll
  for (int j=0;j<4;j++){
    GLD(aSrc[j], &As[0][(t + j*256)*8]);
    GLD(bSrc[j], &Bs[0][(t + j*256)*8]);
  }

  int swz = lm & 7;
  for (int tk=0; tk<nk; ++tk){
    int cur = tk & 1;
    if (tk+1 < nk){
      int kt = (tk+1) << 6;
      #pragma unroll
      for (int j=0;j<4;j++){
        GLD(aSrc[j]+kt, &As[cur^1][(t + j*256)*8]);
        GLD(bSrc[j]+kt, &Bs[cur^1][(t + j*256)*8]);
      }
      asm volatile("s_waitcnt vmcnt(8)" ::: "memory");
    } else {
      asm volatile("s_waitcnt vmcnt(0)" ::: "memory");
    }
    __builtin_amdgcn_s_barrier();
    asm volatile("" ::: "memory");
    const unsigned short* Ac = &As[cur][0];
    const unsigned short* Bc = &Bs[cur][0];
    #pragma unroll
    for (int kk=0;kk<2;kk++){
      int ch = ((kk*4 + lg) ^ swz) * 8;
      ushort8 af[4], bfr[4];
      #pragma unroll
      for (int m=0;m<4;m++) af[m] = *(const ushort8*)(Ac + (wr*64 + m*16 + lm)*64 + ch);
      #pragma unroll
      for (int n=0;n<4;n++) bfr[n] = *(const ushort8*)(Bc + (wc*64 + n*16 + lm)*64 + ch);
      #pragma unroll
      for (int m=0;m<4;m++)
        #pragma unroll
        for (int n=0;n<4;n++)
          acc[m][n] = mfma16(af[m], bfr[n], acc[m][n]);
    }
    asm volatile("" ::: "memory");
    __builtin_amdgcn_s_barrier();
  }

  #pragma unroll
  for (int m=0;m<4;m++){
    int rbase = row0 + wr*64 + m*16 + lg*4;
    #pragma unroll
    for (int n=0;n<4;n++){
      int cc = col0 + wc*64 + n*16 + lm;
      if (cc < Ncols){
        float bv = 0.f;
        if (BIAS) bv = bias[cc];
        #pragma unroll
        for (int rr=0;rr<4;rr++){
          float v = acc[m][n][rr] + bv;
          if (RELU) v = fmaxf(v, 0.f);
          if (RES) v += Res[(size_t)(rbase+rr)*ldres + cc];
          if (OUTF) Cf[(size_t)(rbase+rr)*ldcf + cc] = v;
          if (OUTB) Cb[(size_t)(rbase+rr)*ldcb + cc] = f2bf(v);
        }
      }
    }
  }
}

// ---------------- GEMM 64x64 tile, BK=64, FULL (r&7) swizzle, 2-buf, XCD-chunked ----------------
template<bool BIAS, bool RELU, bool RES, bool OUTF, bool OUTB>
__global__ __launch_bounds__(256) void gemm64_kernel(
    const unsigned short* __restrict__ A, int lda,
    const unsigned short* __restrict__ Bw, int ldb,
    const float* __restrict__ bias,
    const float* __restrict__ Res, int ldres,
    float* __restrict__ Cf, int ldcf,
    unsigned short* __restrict__ Cb, int ldcb,
    int Ncols, int K)
{
  __shared__ __align__(128) unsigned short As[2][64*64];
  __shared__ __align__(128) unsigned short Bs[2][64*64];
  int t = threadIdx.x;
  int wid = t >> 6, lane = t & 63;
  int wr = wid >> 1, wc = wid & 1;
  int lg = lane >> 4, lm = lane & 15;
  int orig = blockIdx.y*gridDim.x + blockIdx.x;
  int nwg = gridDim.x*gridDim.y;
  int wg = ((orig & 7) * (nwg >> 3)) + (orig >> 3);
  int bx = wg % gridDim.x, by = wg / gridDim.x;
  int row0 = by * 64;
  int col0 = bx * 64;

  int ar0 = t >> 3;
  int ar1 = ar0 + 32;
  int aq = (t & 7) ^ (ar0 & 7);   // full 3-bit source pre-swizzle ((ar0+32)&7 == ar0&7)
  const unsigned short* a0 = A + (size_t)(row0+ar0)*lda + aq*8;
  const unsigned short* a1 = A + (size_t)(row0+ar1)*lda + aq*8;
  int br0 = col0+ar0; if (br0 >= Ncols) br0 = Ncols-1;
  int br1 = col0+ar1; if (br1 >= Ncols) br1 = Ncols-1;
  const unsigned short* b0 = Bw + (size_t)br0*ldb + aq*8;
  const unsigned short* b1 = Bw + (size_t)br1*ldb + aq*8;
  int l0 = t*8, l1 = (t+256)*8;

  f32x4 acc[2][2];
  #pragma unroll
  for (int m=0;m<2;m++)
    #pragma unroll
    for (int n=0;n<2;n++) acc[m][n] = f32x4{0.f,0.f,0.f,0.f};

  int nk = K >> 6;
  GLD(a0, &As[0][l0]); GLD(b0, &Bs[0][l0]);
  GLD(a1, &As[0][l1]); GLD(b1, &Bs[0][l1]);

  int swz = lm & 7;
  for (int tk=0; tk<nk; ++tk){
    int cur = tk & 1;
    if (tk+1 < nk){
      int koff = (tk+1) << 6;
      GLD(a0+koff, &As[cur^1][l0]); GLD(b0+koff, &Bs[cur^1][l0]);
      GLD(a1+koff, &As[cur^1][l1]); GLD(b1+koff, &Bs[cur^1][l1]);
      asm volatile("s_waitcnt vmcnt(4)" ::: "memory");
    } else {
      asm volatile("s_waitcnt vmcnt(0)" ::: "memory");
    }
    __builtin_amdgcn_s_barrier();
    asm volatile("" ::: "memory");
    const unsigned short* Ac = &As[cur][0];
    const unsigned short* Bc = &Bs[cur][0];
    #pragma unroll
    for (int kk=0;kk<2;kk++){
      int ch = ((kk*4 + lg) ^ swz) * 8;
      ushort8 af[2], bfr[2];
      #pragma unroll
      for (int m=0;m<2;m++) af[m] = *(const ushort8*)(Ac + (wr*32 + m*16 + lm)*64 + ch);
      #pragma unroll
      for (int n=0;n<2;n++) bfr[n] = *(const ushort8*)(Bc + (wc*32 + n*16 + lm)*64 + ch);
      #pragma unroll
      for (int m=0;m<2;m++)
        #pragma unroll
        for (int n=0;n<2;n++)
          acc[m][n] = mfma16(af[m], bfr[n], acc[m][n]);
    }
    asm volatile("" ::: "memory");
    __builtin_amdgcn_s_barrier();
  }

  #pragma unroll
  for (int m=0;m<2;m++){
    int rbase = row0 + wr*32 + m*16 + lg*4;
    #pragma unroll
    for (int n=0;n<2;n++){
      int cc = col0 + wc*32 + n*16 + lm;
      if (cc < Ncols){
        float bv = 0.f;
        if (BIAS) bv = bias[cc];
        #pragma unroll
        for (int rr=0;rr<4;rr++){
          float v = acc[m][n][rr] + bv;
          if (RELU) v = fmaxf(v, 0.f);
          if (RES) v += Res[(size_t)(rbase+rr)*ldres + cc];
          if (OUTF) Cf[(size_t)(rbase+rr)*ldcf + cc] = v;
          if (OUTB) Cb[(size_t)(rbase+rr)*ldcb + cc] = f2bf(v);
        }
      }
    }
  }
}

// ---------------- flash attention, KV-split=4, KVBLK=32, XCD-grouped dispatch
// qkv bf16 [row][h*192 + {V:0,Q:64,K:128}+d]; mb = additive mask bias (0 / -1e30)
__global__ __launch_bounds__(256) void attn_kernel(const unsigned short* __restrict__ qkv,
    const float* __restrict__ mb, unsigned short* __restrict__ op, float* __restrict__ lpp){
  int t = threadIdx.x; int wid = t>>6, lane = t&63, lg = lane>>4, lm = lane&15;
  int Lid = blockIdx.x + gridDim.x*(blockIdx.y + gridDim.y*blockIdx.z);
  int qt = Lid / NGRP_;
  int gz = Lid - qt*NGRP_;
  int bh = gz % (B_*NH_);
  int zz = gz / (B_*NH_);
  int b = bh/NH_, h = bh%NH_;
  int q0 = qt*64 + wid*16;
  int k0 = zz * (NT2_*32);
  size_t prow = (size_t)zz*ROWS_ + b*N_;

  __shared__ __align__(128) unsigned short Ks[2][2048];
  __shared__ __align__(128) unsigned short Vs[2][2048];
  __shared__ __align__(16) float maskL[NT2_*32];

  const size_t base = (size_t)b*N_*1920 + (size_t)h*192;
  const size_t kvoff = (size_t)k0*1920;

  int kk0 = t>>3, kc0 = (t&7)^(kk0&7);
  const unsigned short* kS0 = qkv + base + kvoff + 128 + (size_t)kk0*1920 + kc0*8;
  int vk0 = ((t>>5)<<2)|((t>>1)&3), vd0 = (((t>>3)&3)<<1)|(t&1);
  const unsigned short* vS0 = qkv + base + kvoff + (size_t)vk0*1920 + vd0*8;

  ushort8 qf[2];
  #pragma unroll
  for (int ss=0; ss<2; ss++)
    qf[ss] = *(const ushort8*)(qkv + base + (size_t)(q0+lm)*1920 + 64 + ss*32 + lg*8);
  float cb2 = mb[b*N_ + q0 + lm] - 17.3123405f;

  if (t < 128) GLD(mb + b*N_ + k0 + t*4, &maskL[t*4]);
  GLD(kS0, &Ks[0][t*8]);
  GLD(vS0, &Vs[0][t*8]);

  float lp = 0.f;
  f32x4 o[4];
  #pragma unroll
  for (int dn=0;dn<4;dn++) o[dn] = f32x4{0.f,0.f,0.f,0.f};

  for (int ii=0; ii<NT2_; ++ii){
    int cur = ii & 1;
    if (ii < NT2_ - 1){
      const size_t adv = (size_t)(ii+1)*32*1920;
      GLD(kS0+adv, &Ks[1-cur][t*8]);
      GLD(vS0+adv, &Vs[1-cur][t*8]);
      asm volatile("s_waitcnt vmcnt(2)" ::: "memory");
    } else {
      asm volatile("s_waitcnt vmcnt(0)" ::: "memory");
    }
    __builtin_amdgcn_s_barrier();
    asm volatile("" ::: "memory");

    const unsigned short* Kc = &Ks[cur][0];
    f32x4 sf[2];
    #pragma unroll
    for (int c=0;c<2;c++){
      int krow = c*16 + lm;
      f32x4 s = f32x4{0.f,0.f,0.f,0.f};
      #pragma unroll
      for (int ss=0;ss<2;ss++){
        ushort8 kf = *(const ushort8*)(Kc + (krow*8 + ((ss*4+lg)^(krow&7)))*8);
        s = mfma16(kf, qf[ss], s);
      }
      sf[c] = s;
    }
    f32x4 mkv[2];
    #pragma unroll
    for (int c=0;c<2;c++) mkv[c] = *(const f32x4*)&maskL[ii*32 + c*16 + lg*4];

    unsigned vsb = (unsigned)(size_t)(__attribute__((address_space(3))) unsigned short*)&Vs[cur][0];
    unsigned a0 = vsb + lg*512 + lm*8;
    u32x2 vb[2][4];
    asm volatile(
      "ds_read_b64_tr_b16 %0, %4 offset:0\n\t"
      "ds_read_b64_tr_b16 %1, %4 offset:128\n\t"
      "ds_read_b64_tr_b16 %2, %4 offset:256\n\t"
      "ds_read_b64_tr_b16 %3, %4 offset:384"
      : "=&v"(vb[0][0]),"=&v"(vb[0][1]),"=&v"(vb[0][2]),"=&v"(vb[0][3]) : "v"(a0));
    asm volatile(
      "ds_read_b64_tr_b16 %0, %4 offset:2048\n\t"
      "ds_read_b64_tr_b16 %1, %4 offset:2176\n\t"
      "ds_read_b64_tr_b16 %2, %4 offset:2304\n\t"
      "ds_read_b64_tr_b16 %3, %4 offset:2432"
      : "=&v"(vb[1][0]),"=&v"(vb[1][1]),"=&v"(vb[1][2]),"=&v"(vb[1][3]) : "v"(a0));

    float pm[2][4]; bf16x4 pa[2];
    #pragma unroll
    for (int c=0;c<2;c++){
      #pragma unroll
      for (int r=0;r<4;r++){
        float x = fmaf(sf[c][r], 0.18033688f, cb2 + mkv[c][r]);
        pm[c][r] = __builtin_amdgcn_exp2f(x);
      }
      lp += (pm[c][0]+pm[c][1]) + (pm[c][2]+pm[c][3]);
      pa[c] = bf16x4{(__bf16)pm[c][0], (__bf16)pm[c][1], (__bf16)pm[c][2], (__bf16)pm[c][3]};
    }

#define PVM(dn_, c_) asm("v_mfma_f32_16x16x16_bf16 %0, %1, %2, %0" \
      : "+v"(o[dn_]) : "v"(__builtin_bit_cast(u32x2, pa[c_])), "v"(vb[c_][dn_]))
    asm volatile("s_waitcnt lgkmcnt(4)" ::: "memory");
    __builtin_amdgcn_sched_barrier(0);
    __builtin_amdgcn_s_setprio(1);
    PVM(0,0); PVM(1,0); PVM(2,0); PVM(3,0);
    asm volatile("s_waitcnt lgkmcnt(0)" ::: "memory");
    __builtin_amdgcn_sched_barrier(0);
    PVM(0,1); PVM(1,1); PVM(2,1); PVM(3,1);
    __builtin_amdgcn_s_setprio(0);
#undef PVM
    asm volatile("" ::: "memory");
    __builtin_amdgcn_s_barrier();
  }

  float s = lp;
  s += __shfl_xor(s, 16, 64);
  s += __shfl_xor(s, 32, 64);
  if (lg == 0) lpp[(prow + q0 + lm)*NH_ + h] = s;
  #pragma unroll
  for (int r=0;r<4;r++){
    unsigned short* ob = op + (prow + q0 + lg*4 + r)*DIM_ + h*64;
    #pragma unroll
    for (int dn=0;dn<4;dn++)
      ob[dn*16 + lm] = f2bf(o[dn][r]);
  }
}

// ---------------- attention split-combine: sum 4 bf16 partials, normalize, leaky, bf16 ----------------
__global__ __launch_bounds__(256) void attnred_kernel(const unsigned short* __restrict__ op,
    const float* __restrict__ lpp, unsigned short* __restrict__ att){
  int idx = blockIdx.x*256 + threadIdx.x;      // [0, ROWS_*80)
  int row = idx / 80;
  int c8 = (idx - row*80) * 8;
  int h = c8 >> 6;
  float l = 0.f;
  #pragma unroll
  for (int s=0;s<NSPLIT_;s++) l += lpp[((size_t)s*ROWS_ + row)*NH_ + h];
  float inv = 1.0f / fmaxf(l, 1e-30f);
  float acc[8] = {0.f,0.f,0.f,0.f,0.f,0.f,0.f,0.f};
  #pragma unroll
  for (int s=0;s<NSPLIT_;s++){
    ushort8 v = *(const ushort8*)(op + ((size_t)s*ROWS_ + row)*DIM_ + c8);
    #pragma unroll
    for (int j=0;j<8;j++) acc[j] += __builtin_bit_cast(float, (unsigned)v[j] << 16);
  }
  ushort8 rr;
  #pragma unroll
  for (int j=0;j<8;j++){
    float v = acc[j] * inv;
    v = (v >= 0.f) ? v : 0.01f*v;   // leaky_relu fused
    rr[j] = f2bf(v);
  }
  *(ushort8*)(att + (size_t)row*DIM_ + c8) = rr;
}

// ---------------- final output dot ----------------
__global__ __launch_bounds__(256) void out_kernel(const float* __restrict__ hf,
    const float* __restrict__ ow, const float* __restrict__ ob, float* __restrict__ out){
  int lane = threadIdx.x & 63;
  int row = blockIdx.x*4 + (threadIdx.x>>6);
  const float* x = hf + (size_t)row*FDIM_;
  float s = 0.f;
  for (int j=lane;j<FDIM_;j+=64) s += x[j]*ow[j];
  #pragma unroll
  for (int off=1; off<64; off<<=1) s += __shfl_xor(s, off, 64);
  if (lane==0) out[row] = s + ob[0];
}

extern "C" void kernel_launch(void* const* d_in, const int* in_sizes, int n_in,
                              void* d_out, int out_size, void* d_ws, size_t ws_size,
                              hipStream_t stream)
{
  const float* x_feats = (const float*)d_in[0];
  const int*   x_toks  = (const int*)d_in[1];
  const float* mask    = (const float*)d_in[2];
  const float* emb0    = (const float*)d_in[3];
  const float* emb1    = (const float*)d_in[4];
  const float* feat_w  = (const float*)d_in[5];
  const float* feat_b  = (const float*)d_in[6];
  const float* qkv_w   = (const float*)d_in[7];
  const float* qkv_b   = (const float*)d_in[8];
  const float* o_w     = (const float*)d_in[9];
  const float* ln1_g   = (const float*)d_in[10];
  const float* ln1_b   = (const float*)d_in[11];
  const float* ln2_g   = (const float*)d_in[12];
  const float* ln2_b   = (const float*)d_in[13];
  const float* p1_w    = (const float*)d_in[14];
  const float* p1_b    = (const float*)d_in[15];
  const float* p2_w    = (const float*)d_in[16];
  const float* p2_b    = (const float*)d_in[17];
  const float* fn_g    = (const float*)d_in[18];
  const float* fn_b    = (const float*)d_in[19];
  const float* lin1_w  = (const float*)d_in[20];
  const float* lin1_b  = (const float*)d_in[21];
  const float* rb1_w   = (const float*)d_in[22];
  const float* rb1_b   = (const float*)d_in[23];
  const float* rb2_w   = (const float*)d_in[24];
  const float* rb2_b   = (const float*)d_in[25];
  const float* out_w   = (const float*)d_in[26];
  const float* out_b   = (const float*)d_in[27];
  float* out = (float*)d_out;

  char* w = (char*)d_ws;
  auto alloc = [&](size_t bytes)->void*{ void* p = (void*)w; w += (bytes + 255) & ~(size_t)255; return p; };

  float* Z              = (float*)alloc((size_t)ROWS_*DIM_*4);
  unsigned short* Zn    = (unsigned short*)alloc((size_t)ROWS_*DIM_*2);
  unsigned short* qkvB  = (unsigned short*)alloc((size_t)ROWS_*1920*2);
  unsigned short* attB  = (unsigned short*)alloc((size_t)ROWS_*DIM_*2);
  unsigned short* Hb    = (unsigned short*)alloc((size_t)ROWS_*DINNER_*2);
  float* hf             = (float*)alloc((size_t)ROWS_*FDIM_*4);
  unsigned short* hb1   = (unsigned short*)alloc((size_t)ROWS_*FDIMP_*2);
  unsigned short* hb2   = (unsigned short*)alloc((size_t)ROWS_*FDIMP_*2);
  float* mbb            = (float*)alloc((size_t)ROWS_*4);
  unsigned short* opart = (unsigned short*)alloc((size_t)NSPLIT_*ROWS_*DIM_*2);
  float* lpart          = (float*)alloc((size_t)NSPLIT_*ROWS_*NH_*4);
  unsigned short* qkvw  = (unsigned short*)alloc((size_t)L_*1920*DIM_*2);
  unsigned short* oww   = (unsigned short*)alloc((size_t)L_*DIM_*DIM_*2);
  unsigned short* p1w   = (unsigned short*)alloc((size_t)L_*DINNER_*DIM_*2);
  unsigned short* p2w   = (unsigned short*)alloc((size_t)L_*DIM_*DINNER_*2);
  unsigned short* l1w   = (unsigned short*)alloc((size_t)FDIM_*DIM_*2);
  unsigned short* r1w   = (unsigned short*)alloc((size_t)FDIM_*FDIMP_*2);
  unsigned short* r2w   = (unsigned short*)alloc((size_t)FDIM_*FDIMP_*2);

  prep_kernel<<<2048,256,0,stream>>>(qkv_w, o_w, p1_w, p2_w, lin1_w, rb1_w, rb2_w, mask,
      qkvw, oww, p1w, p2w, l1w, r1w, r2w,
      (unsigned int*)hb1, (unsigned int*)hb2, mbb);

  embed_kernel<<<ROWS_,256,0,stream>>>(x_feats, x_toks, emb0, emb1, feat_w, feat_b, Z);

  for (int l=0; l<L_; l++){
    ln_kernel<<<ROWS_/4,256,0,stream>>>(Z, ln1_g + l*DIM_, ln1_b + l*DIM_, Zn);
    gemm_kernel<true,false,false,false,true><<<dim3(15,32),256,0,stream>>>(
        Zn, DIM_, qkvw + (size_t)l*1920*DIM_, DIM_, qkv_b + l*1920,
        nullptr, 0, nullptr, 0, qkvB, 1920, 1920, DIM_);
    attn_kernel<<<dim3(N_/64, B_*NH_, NSPLIT_),256,0,stream>>>(qkvB, mbb, opart, lpart);
    attnred_kernel<<<ROWS_*80/256,256,0,stream>>>(opart, lpart, attB);
    gemm64_kernel<false,false,true,true,false><<<dim3(10,64),256,0,stream>>>(
        attB, DIM_, oww + (size_t)l*DIM_*DIM_, DIM_, nullptr,
        Z, DIM_, Z, DIM_, nullptr, 0, DIM_, DIM_);
    ln_kernel<<<ROWS_/4,256,0,stream>>>(Z, ln2_g + l*DIM_, ln2_b + l*DIM_, Zn);
    gemm_kernel<true,true,false,false,true><<<dim3(20,32),256,0,stream>>>(
        Zn, DIM_, p1w + (size_t)l*DINNER_*DIM_, DIM_, p1_b + l*DINNER_,
        nullptr, 0, nullptr, 0, Hb, DINNER_, DINNER_, DIM_);
    gemm64_kernel<true,false,true,true,false><<<dim3(10,64),256,0,stream>>>(
        Hb, DINNER_, p2w + (size_t)l*DIM_*DINNER_, DINNER_, p2_b + l*DIM_,
        Z, DIM_, Z, DIM_, nullptr, 0, DIM_, DINNER_);
  }

  ln_kernel<<<ROWS_/4,256,0,stream>>>(Z, fn_g, fn_b, Zn);
  gemm64_kernel<true,false,false,true,true><<<dim3(5,64),256,0,stream>>>(
      Zn, DIM_, l1w, DIM_, lin1_b, nullptr, 0, hf, FDIM_, hb1, FDIMP_, FDIM_, DIM_);
  gemm64_kernel<true,true,false,false,true><<<dim3(5,64),256,0,stream>>>(
      hb1, FDIMP_, r1w, FDIMP_, rb1_b, nullptr, 0, nullptr, 0, hb2, FDIMP_, FDIM_, FDIMP_);
  gemm64_kernel<true,false,true,true,false><<<dim3(5,64),256,0,stream>>>(
      hb2, FDIMP_, r2w, FDIMP_, rb2_b, hf, FDIM_, hf, FDIM_, nullptr, 0, FDIM_, FDIMP_);
  out_kernel<<<ROWS_/4,256,0,stream>>>(hf, out_w, out_b, out);
}

// Round 14
// 622.727 us; speedup vs baseline: 1.0306x; 1.0085x over previous
//
#include <hip/hip_runtime.h>

#define B_ 2
#define N_ 2048
#define DIM_ 640
#define NH_ 10
#define DH_ 64
#define DINNER_ 2560
#define L_ 4
#define FDIM_ 280
#define FDIMP_ 320
#define FEATD_ 576
#define NFEAT_ 19
#define ROWS_ (B_*N_)   /* 4096 */
#define NSPLIT_ 4
#define NT2_ 16         /* 32-key tiles per split (512 keys/split) */
#define NGRP_ (B_*NH_*NSPLIT_)   /* 80 (bh,split) groups */

typedef __attribute__((ext_vector_type(8))) unsigned short ushort8;
typedef __attribute__((ext_vector_type(4))) unsigned short ushort4v;
typedef __attribute__((ext_vector_type(4))) unsigned int u32x4;
typedef __attribute__((ext_vector_type(8))) __bf16 bf16x8;
typedef __attribute__((ext_vector_type(4))) __bf16 bf16x4;
typedef __attribute__((ext_vector_type(4))) float f32x4;
typedef __attribute__((ext_vector_type(2))) unsigned int u32x2;

static __device__ __forceinline__ unsigned short f2bf(float f){
  unsigned int u = __builtin_bit_cast(unsigned int, f);
  u += 0x7fffu + ((u >> 16) & 1u);
  return (unsigned short)(u >> 16);
}

static __device__ __forceinline__ void cvt4(const float* __restrict__ s, unsigned short* __restrict__ d){
  f32x4 v = *(const f32x4*)s;
  ushort4v r;
  r[0]=f2bf(v[0]); r[1]=f2bf(v[1]); r[2]=f2bf(v[2]); r[3]=f2bf(v[3]);
  *(ushort4v*)d = r;
}

static __device__ __forceinline__ f32x4 mfma16(ushort8 a, ushort8 b, f32x4 c){
  return __builtin_amdgcn_mfma_f32_16x16x32_bf16(
      __builtin_bit_cast(bf16x8, a), __builtin_bit_cast(bf16x8, b), c, 0, 0, 0);
}

#define GLD(src,dst) __builtin_amdgcn_global_load_lds((const __attribute__((address_space(1))) void*)(src), (__attribute__((address_space(3))) void*)(dst), 16, 0, 0)

// ---------------- fused prep (vectorized x4) ----------------
#define SEG0 4915200
#define SEG1 1638400
#define SEG2 6553600
#define SEG3 6553600
#define SEG4 179200
#define SEG5 89600
#define SEG6 89600
#define SEG7 655360
#define SEG8 655360
#define SEG9 4096
#define E0 SEG0
#define E9 (SEG0+SEG1+SEG2+SEG3+SEG4+SEG5+SEG6+SEG7+SEG8+SEG9)

__global__ __launch_bounds__(256) void prep_kernel(
    const float* __restrict__ qkv_w, const float* __restrict__ o_w,
    const float* __restrict__ p1_w, const float* __restrict__ p2_w,
    const float* __restrict__ lin1_w, const float* __restrict__ rb1_w,
    const float* __restrict__ rb2_w, const float* __restrict__ mask,
    unsigned short* __restrict__ qkvw, unsigned short* __restrict__ oww,
    unsigned short* __restrict__ p1w, unsigned short* __restrict__ p2w,
    unsigned short* __restrict__ l1w, unsigned short* __restrict__ r1w,
    unsigned short* __restrict__ r2w, unsigned int* __restrict__ hb1z,
    unsigned int* __restrict__ hb2z, float* __restrict__ mbb)
{
  for (int i = blockIdx.x*256 + threadIdx.x; i < E9/4; i += gridDim.x*256){
    int j = i*4;
    if (j < E0) { cvt4(qkv_w+j, qkvw+j); continue; }
    j -= E0;
    if (j < SEG1) { cvt4(o_w+j, oww+j); continue; }
    j -= SEG1;
    if (j < SEG2) { cvt4(p1_w+j, p1w+j); continue; }
    j -= SEG2;
    if (j < SEG3) { cvt4(p2_w+j, p2w+j); continue; }
    j -= SEG3;
    if (j < SEG4) { cvt4(lin1_w+j, l1w+j); continue; }
    j -= SEG4;
    if (j < SEG5) {
      #pragma unroll
      for (int e=0;e<4;e++){ int jj=j+e; int r=jj/FDIMP_, c=jj-r*FDIMP_;
        r1w[jj] = (c<FDIM_) ? f2bf(rb1_w[r*FDIM_+c]) : (unsigned short)0; }
      continue; }
    j -= SEG5;
    if (j < SEG6) {
      #pragma unroll
      for (int e=0;e<4;e++){ int jj=j+e; int r=jj/FDIMP_, c=jj-r*FDIMP_;
        r2w[jj] = (c<FDIM_) ? f2bf(rb2_w[r*FDIM_+c]) : (unsigned short)0; }
      continue; }
    j -= SEG6;
    if (j < SEG7) { *(u32x4*)(hb1z+j) = u32x4{0u,0u,0u,0u}; continue; }
    j -= SEG7;
    if (j < SEG8) { *(u32x4*)(hb2z+j) = u32x4{0u,0u,0u,0u}; continue; }
    j -= SEG8;
    {
      f32x4 m = *(const f32x4*)(mask+j);
      f32x4 r;
      #pragma unroll
      for (int e=0;e<4;e++) r[e] = (m[e] > 0.f) ? 0.f : -1e30f;
      *(f32x4*)(mbb+j) = r;
    }
  }
}

// ---------------- embedding: 4 rows/block, per-wave (no barrier) ----------------
__global__ __launch_bounds__(256) void embed_kernel(const float* __restrict__ xf,
    const int* __restrict__ xt, const float* __restrict__ e0, const float* __restrict__ e1,
    const float* __restrict__ fw, const float* __restrict__ fb, float* __restrict__ Z){
  int t = threadIdx.x;
  int wv = t >> 6, lane = t & 63;
  int row = blockIdx.x*4 + wv;
  __shared__ float f[4][NFEAT_];
  if (lane < NFEAT_) f[wv][lane] = xf[row*NFEAT_ + lane];
  float* Zr = Z + (size_t)row*DIM_;
  if (lane < 32) {
    Zr[lane] = e0[xt[row*2]*32 + lane];
  } else {
    Zr[lane] = e1[xt[row*2+1]*32 + (lane-32)];
  }
  for (int fo = lane; fo < FEATD_; fo += 64){
    float acc = fb[fo];
    #pragma unroll
    for (int k=0;k<NFEAT_;k++) acc += f[wv][k]*fw[fo*NFEAT_+k];
    Zr[64 + fo] = acc;
  }
}

// ---------------- layernorm (fp32 in -> bf16 out) ----------------
__global__ __launch_bounds__(256) void ln_kernel(const float* __restrict__ X,
    const float* __restrict__ g, const float* __restrict__ bb,
    unsigned short* __restrict__ out){
  int lane = threadIdx.x & 63;
  int row = blockIdx.x*4 + (threadIdx.x >> 6);
  const float* x = X + (size_t)row*DIM_;
  float v[10]; float s=0.f, sq=0.f;
  #pragma unroll
  for (int j=0;j<10;j++){ float t = x[lane + j*64]; v[j]=t; s+=t; sq+=t*t; }
  #pragma unroll
  for (int off=1; off<64; off<<=1){ s += __shfl_xor(s, off, 64); sq += __shfl_xor(sq, off, 64); }
  float mean = s*(1.f/DIM_);
  float var = sq*(1.f/DIM_) - mean*mean;
  float rstd = rsqrtf(var + 1e-5f);
  unsigned short* o = out + (size_t)row*DIM_;
  #pragma unroll
  for (int j=0;j<10;j++){ int c = lane + j*64; o[c] = f2bf((v[j]-mean)*rstd*g[c] + bb[c]); }
}

// ---------------- GEMM 64x64 tile, BK=64, FULL (r&7) swizzle, 2-buf, XCD-chunked ----------------
template<bool BIAS, bool RELU, bool RES, bool OUTF, bool OUTB>
__global__ __launch_bounds__(256) void gemm64_kernel(
    const unsigned short* __restrict__ A, int lda,
    const unsigned short* __restrict__ Bw, int ldb,
    const float* __restrict__ bias,
    const float* __restrict__ Res, int ldres,
    float* __restrict__ Cf, int ldcf,
    unsigned short* __restrict__ Cb, int ldcb,
    int Ncols, int K)
{
  __shared__ __align__(128) unsigned short As[2][64*64];
  __shared__ __align__(128) unsigned short Bs[2][64*64];
  int t = threadIdx.x;
  int wid = t >> 6, lane = t & 63;
  int wr = wid >> 1, wc = wid & 1;
  int lg = lane >> 4, lm = lane & 15;
  int orig = blockIdx.y*gridDim.x + blockIdx.x;
  int nwg = gridDim.x*gridDim.y;
  int wg = ((orig & 7) * (nwg >> 3)) + (orig >> 3);
  int bx = wg % gridDim.x, by = wg / gridDim.x;
  int row0 = by * 64;
  int col0 = bx * 64;

  int ar0 = t >> 3;
  int ar1 = ar0 + 32;
  int aq = (t & 7) ^ (ar0 & 7);   // full 3-bit source pre-swizzle ((ar0+32)&7 == ar0&7)
  const unsigned short* a0 = A + (size_t)(row0+ar0)*lda + aq*8;
  const unsigned short* a1 = A + (size_t)(row0+ar1)*lda + aq*8;
  int br0 = col0+ar0; if (br0 >= Ncols) br0 = Ncols-1;
  int br1 = col0+ar1; if (br1 >= Ncols) br1 = Ncols-1;
  const unsigned short* b0 = Bw + (size_t)br0*ldb + aq*8;
  const unsigned short* b1 = Bw + (size_t)br1*ldb + aq*8;
  int l0 = t*8, l1 = (t+256)*8;

  f32x4 acc[2][2];
  #pragma unroll
  for (int m=0;m<2;m++)
    #pragma unroll
    for (int n=0;n<2;n++) acc[m][n] = f32x4{0.f,0.f,0.f,0.f};

  int nk = K >> 6;
  GLD(a0, &As[0][l0]); GLD(b0, &Bs[0][l0]);
  GLD(a1, &As[0][l1]); GLD(b1, &Bs[0][l1]);

  int swz = lm & 7;
  for (int tk=0; tk<nk; ++tk){
    int cur = tk & 1;
    if (tk+1 < nk){
      int koff = (tk+1) << 6;
      GLD(a0+koff, &As[cur^1][l0]); GLD(b0+koff, &Bs[cur^1][l0]);
      GLD(a1+koff, &As[cur^1][l1]); GLD(b1+koff, &Bs[cur^1][l1]);
      asm volatile("s_waitcnt vmcnt(4)" ::: "memory");
    } else {
      asm volatile("s_waitcnt vmcnt(0)" ::: "memory");
    }
    __builtin_amdgcn_s_barrier();
    asm volatile("" ::: "memory");
    const unsigned short* Ac = &As[cur][0];
    const unsigned short* Bc = &Bs[cur][0];
    #pragma unroll
    for (int kk=0;kk<2;kk++){
      int ch = ((kk*4 + lg) ^ swz) * 8;
      ushort8 af[2], bfr[2];
      #pragma unroll
      for (int m=0;m<2;m++) af[m] = *(const ushort8*)(Ac + (wr*32 + m*16 + lm)*64 + ch);
      #pragma unroll
      for (int n=0;n<2;n++) bfr[n] = *(const ushort8*)(Bc + (wc*32 + n*16 + lm)*64 + ch);
      #pragma unroll
      for (int m=0;m<2;m++)
        #pragma unroll
        for (int n=0;n<2;n++)
          acc[m][n] = mfma16(af[m], bfr[n], acc[m][n]);
    }
    asm volatile("" ::: "memory");
    __builtin_amdgcn_s_barrier();
  }

  #pragma unroll
  for (int m=0;m<2;m++){
    int rbase = row0 + wr*32 + m*16 + lg*4;
    #pragma unroll
    for (int n=0;n<2;n++){
      int cc = col0 + wc*32 + n*16 + lm;
      if (cc < Ncols){
        float bv = 0.f;
        if (BIAS) bv = bias[cc];
        #pragma unroll
        for (int rr=0;rr<4;rr++){
          float v = acc[m][n][rr] + bv;
          if (RELU) v = fmaxf(v, 0.f);
          if (RES) v += Res[(size_t)(rbase+rr)*ldres + cc];
          if (OUTF) Cf[(size_t)(rbase+rr)*ldcf + cc] = v;
          if (OUTB) Cb[(size_t)(rbase+rr)*ldcb + cc] = f2bf(v);
        }
      }
    }
  }
}

// ---------------- flash attention, KV-split=4, KVBLK=32, XCD-grouped dispatch
// qkv bf16 [row][h*192 + {V:0,Q:64,K:128}+d]; mb = additive mask bias (0 / -1e30)
__global__ __launch_bounds__(256) void attn_kernel(const unsigned short* __restrict__ qkv,
    const float* __restrict__ mb, unsigned short* __restrict__ op, float* __restrict__ lpp){
  int t = threadIdx.x; int wid = t>>6, lane = t&63, lg = lane>>4, lm = lane&15;
  int Lid = blockIdx.x + gridDim.x*(blockIdx.y + gridDim.y*blockIdx.z);
  int qt = Lid / NGRP_;
  int gz = Lid - qt*NGRP_;
  int bh = gz % (B_*NH_);
  int zz = gz / (B_*NH_);
  int b = bh/NH_, h = bh%NH_;
  int q0 = qt*64 + wid*16;
  int k0 = zz * (NT2_*32);
  size_t prow = (size_t)zz*ROWS_ + b*N_;

  __shared__ __align__(128) unsigned short Ks[2][2048];
  __shared__ __align__(128) unsigned short Vs[2][2048];
  __shared__ __align__(16) float maskL[NT2_*32];

  const size_t base = (size_t)b*N_*1920 + (size_t)h*192;
  const size_t kvoff = (size_t)k0*1920;

  int kk0 = t>>3, kc0 = (t&7)^(kk0&7);
  const unsigned short* kS0 = qkv + base + kvoff + 128 + (size_t)kk0*1920 + kc0*8;
  int vk0 = ((t>>5)<<2)|((t>>1)&3), vd0 = (((t>>3)&3)<<1)|(t&1);
  const unsigned short* vS0 = qkv + base + kvoff + (size_t)vk0*1920 + vd0*8;

  ushort8 qf[2];
  #pragma unroll
  for (int ss=0; ss<2; ss++)
    qf[ss] = *(const ushort8*)(qkv + base + (size_t)(q0+lm)*1920 + 64 + ss*32 + lg*8);
  float cb2 = mb[b*N_ + q0 + lm] - 17.3123405f;

  if (t < 128) GLD(mb + b*N_ + k0 + t*4, &maskL[t*4]);
  GLD(kS0, &Ks[0][t*8]);
  GLD(vS0, &Vs[0][t*8]);

  float lp = 0.f;
  f32x4 o[4];
  #pragma unroll
  for (int dn=0;dn<4;dn++) o[dn] = f32x4{0.f,0.f,0.f,0.f};

  for (int ii=0; ii<NT2_; ++ii){
    int cur = ii & 1;
    if (ii < NT2_ - 1){
      const size_t adv = (size_t)(ii+1)*32*1920;
      GLD(kS0+adv, &Ks[1-cur][t*8]);
      GLD(vS0+adv, &Vs[1-cur][t*8]);
      asm volatile("s_waitcnt vmcnt(2)" ::: "memory");
    } else {
      asm volatile("s_waitcnt vmcnt(0)" ::: "memory");
    }
    __builtin_amdgcn_s_barrier();
    asm volatile("" ::: "memory");

    const unsigned short* Kc = &Ks[cur][0];
    f32x4 sf[2];
    #pragma unroll
    for (int c=0;c<2;c++){
      int krow = c*16 + lm;
      f32x4 s = f32x4{0.f,0.f,0.f,0.f};
      #pragma unroll
      for (int ss=0;ss<2;ss++){
        ushort8 kf = *(const ushort8*)(Kc + (krow*8 + ((ss*4+lg)^(krow&7)))*8);
        s = mfma16(kf, qf[ss], s);
      }
      sf[c] = s;
    }
    f32x4 mkv[2];
    #pragma unroll
    for (int c=0;c<2;c++) mkv[c] = *(const f32x4*)&maskL[ii*32 + c*16 + lg*4];

    unsigned vsb = (unsigned)(size_t)(__attribute__((address_space(3))) unsigned short*)&Vs[cur][0];
    unsigned a0 = vsb + lg*512 + lm*8;
    u32x2 vb[2][4];
    asm volatile(
      "ds_read_b64_tr_b16 %0, %4 offset:0\n\t"
      "ds_read_b64_tr_b16 %1, %4 offset:128\n\t"
      "ds_read_b64_tr_b16 %2, %4 offset:256\n\t"
      "ds_read_b64_tr_b16 %3, %4 offset:384"
      : "=&v"(vb[0][0]),"=&v"(vb[0][1]),"=&v"(vb[0][2]),"=&v"(vb[0][3]) : "v"(a0));
    asm volatile(
      "ds_read_b64_tr_b16 %0, %4 offset:2048\n\t"
      "ds_read_b64_tr_b16 %1, %4 offset:2176\n\t"
      "ds_read_b64_tr_b16 %2, %4 offset:2304\n\t"
      "ds_read_b64_tr_b16 %3, %4 offset:2432"
      : "=&v"(vb[1][0]),"=&v"(vb[1][1]),"=&v"(vb[1][2]),"=&v"(vb[1][3]) : "v"(a0));

    float pm[2][4]; bf16x4 pa[2];
    #pragma unroll
    for (int c=0;c<2;c++){
      #pragma unroll
      for (int r=0;r<4;r++){
        float x = fmaf(sf[c][r], 0.18033688f, cb2 + mkv[c][r]);
        pm[c][r] = __builtin_amdgcn_exp2f(x);
      }
      lp += (pm[c][0]+pm[c][1]) + (pm[c][2]+pm[c][3]);
      pa[c] = bf16x4{(__bf16)pm[c][0], (__bf16)pm[c][1], (__bf16)pm[c][2], (__bf16)pm[c][3]};
    }

#define PVM(dn_, c_) asm("v_mfma_f32_16x16x16_bf16 %0, %1, %2, %0" \
      : "+v"(o[dn_]) : "v"(__builtin_bit_cast(u32x2, pa[c_])), "v"(vb[c_][dn_]))
    asm volatile("s_waitcnt lgkmcnt(4)" ::: "memory");
    __builtin_amdgcn_sched_barrier(0);
    __builtin_amdgcn_s_setprio(1);
    PVM(0,0); PVM(1,0); PVM(2,0); PVM(3,0);
    asm volatile("s_waitcnt lgkmcnt(0)" ::: "memory");
    __builtin_amdgcn_sched_barrier(0);
    PVM(0,1); PVM(1,1); PVM(2,1); PVM(3,1);
    __builtin_amdgcn_s_setprio(0);
#undef PVM
    asm volatile("" ::: "memory");
    __builtin_amdgcn_s_barrier();
  }

  float s = lp;
  s += __shfl_xor(s, 16, 64);
  s += __shfl_xor(s, 32, 64);
  if (lg == 0) lpp[(prow + q0 + lm)*NH_ + h] = s;
  #pragma unroll
  for (int r=0;r<4;r++){
    unsigned short* ob = op + (prow + q0 + lg*4 + r)*DIM_ + h*64;
    #pragma unroll
    for (int dn=0;dn<4;dn++)
      ob[dn*16 + lm] = f2bf(o[dn][r]);
  }
}

// ---------------- attention split-combine: sum 4 bf16 partials, normalize, leaky, bf16 ----------------
__global__ __launch_bounds__(256) void attnred_kernel(const unsigned short* __restrict__ op,
    const float* __restrict__ lpp, unsigned short* __restrict__ att){
  int idx = blockIdx.x*256 + threadIdx.x;      // [0, ROWS_*80)
  int row = idx / 80;
  int c8 = (idx - row*80) * 8;
  int h = c8 >> 6;
  float l = 0.f;
  #pragma unroll
  for (int s=0;s<NSPLIT_;s++) l += lpp[((size_t)s*ROWS_ + row)*NH_ + h];
  float inv = 1.0f / fmaxf(l, 1e-30f);
  float acc[8] = {0.f,0.f,0.f,0.f,0.f,0.f,0.f,0.f};
  #pragma unroll
  for (int s=0;s<NSPLIT_;s++){
    ushort8 v = *(const ushort8*)(op + ((size_t)s*ROWS_ + row)*DIM_ + c8);
    #pragma unroll
    for (int j=0;j<8;j++) acc[j] += __builtin_bit_cast(float, (unsigned)v[j] << 16);
  }
  ushort8 rr;
  #pragma unroll
  for (int j=0;j<8;j++){
    float v = acc[j] * inv;
    v = (v >= 0.f) ? v : 0.01f*v;   // leaky_relu fused
    rr[j] = f2bf(v);
  }
  *(ushort8*)(att + (size_t)row*DIM_ + c8) = rr;
}

// ---------------- final output dot ----------------
__global__ __launch_bounds__(256) void out_kernel(const float* __restrict__ hf,
    const float* __restrict__ ow, const float* __restrict__ ob, float* __restrict__ out){
  int lane = threadIdx.x & 63;
  int row = blockIdx.x*4 + (threadIdx.x>>6);
  const float* x = hf + (size_t)row*FDIM_;
  float s = 0.f;
  for (int j=lane;j<FDIM_;j+=64) s += x[j]*ow[j];
  #pragma unroll
  for (int off=1; off<64; off<<=1) s += __shfl_xor(s, off, 64);
  if (lane==0) out[row] = s + ob[0];
}

extern "C" void kernel_launch(void* const* d_in, const int* in_sizes, int n_in,
                              void* d_out, int out_size, void* d_ws, size_t ws_size,
                              hipStream_t stream)
{
  const float* x_feats = (const float*)d_in[0];
  const int*   x_toks  = (const int*)d_in[1];
  const float* mask    = (const float*)d_in[2];
  const float* emb0    = (const float*)d_in[3];
  const float* emb1    = (const float*)d_in[4];
  const float* feat_w  = (const float*)d_in[5];
  const float* feat_b  = (const float*)d_in[6];
  const float* qkv_w   = (const float*)d_in[7];
  const float* qkv_b   = (const float*)d_in[8];
  const float* o_w     = (const float*)d_in[9];
  const float* ln1_g   = (const float*)d_in[10];
  const float* ln1_b   = (const float*)d_in[11];
  const float* ln2_g   = (const float*)d_in[12];
  const float* ln2_b   = (const float*)d_in[13];
  const float* p1_w    = (const float*)d_in[14];
  const float* p1_b    = (const float*)d_in[15];
  const float* p2_w    = (const float*)d_in[16];
  const float* p2_b    = (const float*)d_in[17];
  const float* fn_g    = (const float*)d_in[18];
  const float* fn_b    = (const float*)d_in[19];
  const float* lin1_w  = (const float*)d_in[20];
  const float* lin1_b  = (const float*)d_in[21];
  const float* rb1_w   = (const float*)d_in[22];
  const float* rb1_b   = (const float*)d_in[23];
  const float* rb2_w   = (const float*)d_in[24];
  const float* rb2_b   = (const float*)d_in[25];
  const float* out_w   = (const float*)d_in[26];
  const float* out_b   = (const float*)d_in[27];
  float* out = (float*)d_out;

  char* w = (char*)d_ws;
  auto alloc = [&](size_t bytes)->void*{ void* p = (void*)w; w += (bytes + 255) & ~(size_t)255; return p; };

  float* Z              = (float*)alloc((size_t)ROWS_*DIM_*4);
  unsigned short* Zn    = (unsigned short*)alloc((size_t)ROWS_*DIM_*2);
  unsigned short* qkvB  = (unsigned short*)alloc((size_t)ROWS_*1920*2);
  unsigned short* attB  = (unsigned short*)alloc((size_t)ROWS_*DIM_*2);
  unsigned short* Hb    = (unsigned short*)alloc((size_t)ROWS_*DINNER_*2);
  float* hf             = (float*)alloc((size_t)ROWS_*FDIM_*4);
  unsigned short* hb1   = (unsigned short*)alloc((size_t)ROWS_*FDIMP_*2);
  unsigned short* hb2   = (unsigned short*)alloc((size_t)ROWS_*FDIMP_*2);
  float* mbb            = (float*)alloc((size_t)ROWS_*4);
  unsigned short* opart = (unsigned short*)alloc((size_t)NSPLIT_*ROWS_*DIM_*2);
  float* lpart          = (float*)alloc((size_t)NSPLIT_*ROWS_*NH_*4);
  unsigned short* qkvw  = (unsigned short*)alloc((size_t)L_*1920*DIM_*2);
  unsigned short* oww   = (unsigned short*)alloc((size_t)L_*DIM_*DIM_*2);
  unsigned short* p1w   = (unsigned short*)alloc((size_t)L_*DINNER_*DIM_*2);
  unsigned short* p2w   = (unsigned short*)alloc((size_t)L_*DIM_*DINNER_*2);
  unsigned short* l1w   = (unsigned short*)alloc((size_t)FDIM_*DIM_*2);
  unsigned short* r1w   = (unsigned short*)alloc((size_t)FDIM_*FDIMP_*2);
  unsigned short* r2w   = (unsigned short*)alloc((size_t)FDIM_*FDIMP_*2);

  prep_kernel<<<2048,256,0,stream>>>(qkv_w, o_w, p1_w, p2_w, lin1_w, rb1_w, rb2_w, mask,
      qkvw, oww, p1w, p2w, l1w, r1w, r2w,
      (unsigned int*)hb1, (unsigned int*)hb2, mbb);

  embed_kernel<<<ROWS_/4,256,0,stream>>>(x_feats, x_toks, emb0, emb1, feat_w, feat_b, Z);

  for (int l=0; l<L_; l++){
    ln_kernel<<<ROWS_/4,256,0,stream>>>(Z, ln1_g + l*DIM_, ln1_b + l*DIM_, Zn);
    gemm64_kernel<true,false,false,false,true><<<dim3(30,64),256,0,stream>>>(
        Zn, DIM_, qkvw + (size_t)l*1920*DIM_, DIM_, qkv_b + l*1920,
        nullptr, 0, nullptr, 0, qkvB, 1920, 1920, DIM_);
    attn_kernel<<<dim3(N_/64, B_*NH_, NSPLIT_),256,0,stream>>>(qkvB, mbb, opart, lpart);
    attnred_kernel<<<ROWS_*80/256,256,0,stream>>>(opart, lpart, attB);
    gemm64_kernel<false,false,true,true,false><<<dim3(10,64),256,0,stream>>>(
        attB, DIM_, oww + (size_t)l*DIM_*DIM_, DIM_, nullptr,
        Z, DIM_, Z, DIM_, nullptr, 0, DIM_, DIM_);
    ln_kernel<<<ROWS_/4,256,0,stream>>>(Z, ln2_g + l*DIM_, ln2_b + l*DIM_, Zn);
    gemm64_kernel<true,true,false,false,true><<<dim3(40,64),256,0,stream>>>(
        Zn, DIM_, p1w + (size_t)l*DINNER_*DIM_, DIM_, p1_b + l*DINNER_,
        nullptr, 0, nullptr, 0, Hb, DINNER_, DINNER_, DIM_);
    gemm64_kernel<true,false,true,true,false><<<dim3(10,64),256,0,stream>>>(
        Hb, DINNER_, p2w + (size_t)l*DIM_*DINNER_, DINNER_, p2_b + l*DIM_,
        Z, DIM_, Z, DIM_, nullptr, 0, DIM_, DINNER_);
  }

  ln_kernel<<<ROWS_/4,256,0,stream>>>(Z, fn_g, fn_b, Zn);
  gemm64_kernel<true,false,false,true,true><<<dim3(5,64),256,0,stream>>>(
      Zn, DIM_, l1w, DIM_, lin1_b, nullptr, 0, hf, FDIM_, hb1, FDIMP_, FDIM_, DIM_);
  gemm64_kernel<true,true,false,false,true><<<dim3(5,64),256,0,stream>>>(
      hb1, FDIMP_, r1w, FDIMP_, rb1_b, nullptr, 0, nullptr, 0, hb2, FDIMP_, FDIM_, FDIMP_);
  gemm64_kernel<true,false,true,true,false><<<dim3(5,64),256,0,stream>>>(
      hb2, FDIMP_, r2w, FDIMP_, rb2_b, hf, FDIM_, hf, FDIM_, nullptr, 0, FDIM_, FDIMP_);
  out_kernel<<<ROWS_/4,256,0,stream>>>(hf, out_w, out_b, out);
}